// Round 13
// baseline (258.130 us; speedup 1.0000x reference)
//
#include <hip/hip_runtime.h>
#include <hip/hip_bf16.h>

// Problem constants (GAT_18176301597437)
#define N_NODES 4096
#define F_IN    256
#define KH      8
#define KF      512          // KH*FPH
#define NEG_SLOPE 0.2f
#define EBIAS   4.0f

typedef _Float16 half8v __attribute__((ext_vector_type(8)));   // MFMA f16 A/B
typedef _Float16 half2v __attribute__((ext_vector_type(2)));   // packed f16 pair
typedef __attribute__((ext_vector_type(4))) float floatx4;     // MFMA C/D

union H8U4 { half8v v; unsigned u[4]; };

__device__ __forceinline__ unsigned short f2h(float f) {
    _Float16 h = (_Float16)f;
    unsigned short u; __builtin_memcpy(&u, &h, 2);
    return u;
}
__device__ __forceinline__ half2v asH2(unsigned u) {
    half2v h; __builtin_memcpy(&h, &u, 4);
    return h;
}
__device__ __forceinline__ unsigned asU(half2v h) {
    unsigned u; __builtin_memcpy(&u, &h, 4);
    return u;
}

// ---------- mask_fused v2: tiled, fully coalesced ----------------------------
// Block = (row-group of 64) x (col-chunk c). Reads 64x64 int tile, writes the
// fp32 passthrough (coalesced 256B/row) and 64 CONTIGUOUS bit-words
// bits[c][n0..n0+63] via LDS staging (single 512B store).
__global__ __launch_bounds__(256) void mask_fused(
    const int* __restrict__ mask, float* __restrict__ outm,
    unsigned long long* __restrict__ bits) {
  __shared__ unsigned long long wbuf[64];
  const int tid = threadIdx.x;
  const int w4 = tid >> 6;
  const int lane = tid & 63;
  const int cb = blockIdx.x & 63;          // col chunk
  const int n0 = (blockIdx.x >> 6) * 64;   // row group
  const int colb = cb * 64;
  #pragma unroll
  for (int r = 0; r < 16; ++r) {
    const int row = n0 + w4 * 16 + r;
    const size_t e = (size_t)row * N_NODES + colb + lane;
    const int v = mask[e];
    outm[e] = v ? 1.f : 0.f;
    const unsigned long long b = __ballot(v != 0);
    if (lane == 0) wbuf[w4 * 16 + r] = b;
  }
  __syncthreads();
  if (tid < 64) bits[(size_t)cb * N_NODES + n0 + tid] = wbuf[tid];
}

// ---------- fallback pair (scratch inside out_mask region) ----------
__global__ __launch_bounds__(256) void mask_pack(
    const int* __restrict__ mask, unsigned long long* __restrict__ bits) {
  const size_t idx = (size_t)blockIdx.x * 256 + threadIdx.x;
  const unsigned long long b = __ballot(mask[idx] != 0);
  if ((threadIdx.x & 63) == 0) {
    const size_t w = idx >> 6;
    bits[(w & 63) * (size_t)N_NODES + (w >> 6)] = b;
  }
}
__global__ __launch_bounds__(256) void mask_copy(
    const int* __restrict__ mask, float* __restrict__ outm) {
  const size_t i4 = (size_t)blockIdx.x * 256 + threadIdx.x;
  const int4 mv = ((const int4*)mask)[i4];
  float4 o;
  o.x = mv.x ? 1.f : 0.f; o.y = mv.y ? 1.f : 0.f;
  o.z = mv.z ? 1.f : 0.f; o.w = mv.w ? 1.f : 0.f;
  ((float4*)outm)[i4] = o;
}

// ---------- Kernel A: xe-GEMM + fused hl/EA/EB/blockmax epilogue -------------
// xeB tile = (head k, ft, chunk c): 1024 f16 = [h(2)][f(16)][quad(4)][j(8)].
// EA[k][n/2] = packed f16 pair exp(hr-4); EB = exp(0.2*(hr-4)).
__global__ __launch_bounds__(256) void xe_gemm(
    const float* __restrict__ x,
    const float* __restrict__ Ww,
    const float* __restrict__ Wb,
    const float* __restrict__ al,
    const float* __restrict__ ar,
    unsigned short* __restrict__ xeB,
    float* __restrict__ hl,             // [8][4096]
    unsigned* __restrict__ EA,          // [8][2048]
    unsigned* __restrict__ EB,          // [8][2048]
    float* __restrict__ bmax) {         // [8][64]
  __shared__ float As[32][65];
  __shared__ float Bs[32][65];
  __shared__ float redmax[4];
  const int tid = threadIdx.x;
  const int n0 = blockIdx.x * 64;
  const int j0 = blockIdx.y * 64;
  const int lr = tid >> 2;
  const int lc = (tid & 3) * 8;
  const int ty = tid >> 4;
  const int tx = tid & 15;
  float c[4][4];
  #pragma unroll
  for (int i = 0; i < 4; ++i)
    #pragma unroll
    for (int j = 0; j < 4; ++j) c[i][j] = 0.f;

  for (int f0 = 0; f0 < F_IN; f0 += 32) {
    const float* ap = x  + (size_t)(n0 + lr) * F_IN + f0 + lc;
    const float* bp = Ww + (size_t)(j0 + lr) * F_IN + f0 + lc;
    const float4 a0 = *(const float4*)ap;
    const float4 a1 = *(const float4*)(ap + 4);
    const float4 b0 = *(const float4*)bp;
    const float4 b1 = *(const float4*)(bp + 4);
    __syncthreads();
    As[lc + 0][lr] = a0.x; As[lc + 1][lr] = a0.y;
    As[lc + 2][lr] = a0.z; As[lc + 3][lr] = a0.w;
    As[lc + 4][lr] = a1.x; As[lc + 5][lr] = a1.y;
    As[lc + 6][lr] = a1.z; As[lc + 7][lr] = a1.w;
    Bs[lc + 0][lr] = b0.x; Bs[lc + 1][lr] = b0.y;
    Bs[lc + 2][lr] = b0.z; Bs[lc + 3][lr] = b0.w;
    Bs[lc + 4][lr] = b1.x; Bs[lc + 5][lr] = b1.y;
    Bs[lc + 6][lr] = b1.z; Bs[lc + 7][lr] = b1.w;
    __syncthreads();
    #pragma unroll
    for (int kk = 0; kk < 32; ++kk) {
      const float4 av = *(const float4*)&As[kk][ty * 4];
      const float4 bv = *(const float4*)&Bs[kk][tx * 4];
      const float a4[4] = {av.x, av.y, av.z, av.w};
      const float b4[4] = {bv.x, bv.y, bv.z, bv.w};
      #pragma unroll
      for (int i = 0; i < 4; ++i)
        #pragma unroll
        for (int j = 0; j < 4; ++j) c[i][j] = fmaf(a4[i], b4[j], c[i][j]);
    }
  }
  const float4 wb4 = *(const float4*)(Wb + j0 + tx * 4);
  const float4 al4 = *(const float4*)(al + j0 + tx * 4);
  const float4 ar4 = *(const float4*)(ar + j0 + tx * 4);
  const float wb[4] = {wb4.x, wb4.y, wb4.z, wb4.w};
  const float alv[4] = {al4.x, al4.y, al4.z, al4.w};
  const float arv[4] = {ar4.x, ar4.y, ar4.z, ar4.w};
  float v[4][4];
  float pl[4], pr[4];
  #pragma unroll
  for (int i = 0; i < 4; ++i) {
    float sl = 0.f, sr = 0.f;
    #pragma unroll
    for (int j = 0; j < 4; ++j) {
      v[i][j] = c[i][j] + wb[j];
      sl = fmaf(v[i][j], alv[j], sl);
      sr = fmaf(v[i][j], arv[j], sr);
    }
    pl[i] = sl; pr[i] = sr;
  }
  {
    const int k   = blockIdx.y;
    const int ft  = tx >> 2;
    const int fb  = (tx & 3) * 4;
    const int cc  = blockIdx.x;
    const int h_  = ty >> 3;
    const int qd  = (ty >> 1) & 3;
    const int jj0 = (ty & 1) * 4;
    unsigned short* tile = xeB + ((((size_t)(k * 4 + ft)) * 64 + cc) << 10)
                         + h_ * 512 + qd * 8 + jj0;
    #pragma unroll
    for (int j = 0; j < 4; ++j) {
      ushort4 pk;
      pk.x = f2h(v[0][j]); pk.y = f2h(v[1][j]);
      pk.z = f2h(v[2][j]); pk.w = f2h(v[3][j]);
      *(ushort4*)(tile + (fb + j) * 32) = pk;
    }
  }
  #pragma unroll
  for (int off = 8; off > 0; off >>= 1) {
    #pragma unroll
    for (int i = 0; i < 4; ++i) {
      pl[i] += __shfl_down(pl[i], off);
      pr[i] += __shfl_down(pr[i], off);
    }
  }
  if (tx == 0) {
    const int k = blockIdx.y;
    float4 o0 = {pl[0], pl[1], pl[2], pl[3]};
    *(float4*)(hl + k * N_NODES + n0 + ty * 4) = o0;
    unsigned short e1[4], e2[4];
    #pragma unroll
    for (int i = 0; i < 4; ++i) {
      e1[i] = f2h(__expf(pr[i] - EBIAS));
      e2[i] = f2h(__expf(NEG_SLOPE * (pr[i] - EBIAS)));
    }
    uint2 wa, wbv;
    wa.x  = (unsigned)e1[0] | ((unsigned)e1[1] << 16);
    wa.y  = (unsigned)e1[2] | ((unsigned)e1[3] << 16);
    wbv.x = (unsigned)e2[0] | ((unsigned)e2[1] << 16);
    wbv.y = (unsigned)e2[2] | ((unsigned)e2[3] << 16);
    *(uint2*)(EA + k * 2048 + ((n0 + ty * 4) >> 1)) = wa;
    *(uint2*)(EB + k * 2048 + ((n0 + ty * 4) >> 1)) = wbv;
  }
  float bm = (tx == 0)
      ? fmaxf(fmaxf(pr[0], pr[1]), fmaxf(pr[2], pr[3])) : -1e30f;
  bm = fmaxf(bm, __shfl_xor(bm, 16));
  bm = fmaxf(bm, __shfl_xor(bm, 32));
  if ((tid & 63) == 0) redmax[tid >> 6] = bm;
  __syncthreads();
  if (tid == 0) {
    bmax[blockIdx.y * 64 + blockIdx.x] =
        fmaxf(fmaxf(redmax[0], redmax[1]), fmaxf(redmax[2], redmax[3]));
  }
}

// ---------- Kernel D: fused attention, 32 rows/block, shared B loads ---------
// Block = 256 thr = 4 waves = (32-row group, head); wave = 16 m-chunks.
// Two 16-row MFMA tiles (A: n0..15, B: n0+16..31) share each chunk's B and E
// loads -> half the B traffic, double the per-wave ILP. Two-phase epilogue
// reuses one 20 KB LDS buffer.
__global__ __launch_bounds__(256, 4) void gat_attn(
    const unsigned long long* __restrict__ mbitsT,   // [64 c][4096 n]
    const float* __restrict__ hl,
    const float* __restrict__ bmax,                  // [8][64]
    const unsigned* __restrict__ EA,                 // [8][2048] f16 pairs
    const unsigned* __restrict__ EB,
    const unsigned short* __restrict__ xeB,          // f16 frag tiles
    float* __restrict__ out) {
  __shared__ float lds_acc[4][64][20];   // 20 KB (reused for both phases)
  const int t = threadIdx.x;
  const int w4 = t >> 6;                // wave 0..3 = m-quarter
  const int lane = t & 63;
  const int k  = blockIdx.x >> 7;       // same-k grouping for L2 locality
  const int rg = blockIdx.x & 127;
  const int n0 = rg * 32;
  const int row = lane & 15;
  const int quad = lane >> 4;
  const int q8 = quad * 8;

  float hm = bmax[k * 64 + lane];
  #pragma unroll
  for (int o = 1; o < 64; o <<= 1) hm = fmaxf(hm, __shfl_xor(hm, o));

  const float* hlp = hl + k * N_NODES + n0 + row;
  const float hlA = hlp[0];
  const float hlB = hlp[16];
  const float sA = hlA + hm;
  const float MA = fmaxf(sA, NEG_SLOPE * sA);
  const float sB = hlB + hm;
  const float MB = fmaxf(sB, NEG_SLOPE * sB);
  const float c1Af = __expf(hlA + EBIAS - MA);
  const float c2Af = __expf(NEG_SLOPE * (hlA + EBIAS) - MA);
  const float c1Bf = __expf(hlB + EBIAS - MB);
  const float c2Bf = __expf(NEG_SLOPE * (hlB + EBIAS) - MB);
  const half2v c1A = {(_Float16)c1Af, (_Float16)c1Af};
  const half2v c2A = {(_Float16)c2Af, (_Float16)c2Af};
  const half2v c1B = {(_Float16)c1Bf, (_Float16)c1Bf};
  const half2v c2B = {(_Float16)c2Bf, (_Float16)c2Bf};

  const int c0 = w4 * 16;
  const int cEnd = c0 + 16;

  // running pointers
  const unsigned* pEA = EA + k * 2048 + c0 * 32 + quad * 4;
  const unsigned* pEB = EB + k * 2048 + c0 * 32 + quad * 4;
  const unsigned long long* pM = mbitsT + (size_t)c0 * N_NODES + n0 + row;
  const unsigned short* pB = xeB + (((size_t)k * 4) << 16)
                           + ((size_t)c0 << 10) + row * 32 + q8;

  half8v ones;
  #pragma unroll
  for (int i = 0; i < 8; ++i) ones[i] = (_Float16)1.0f;

  floatx4 accA[4], accB[4];
  #pragma unroll
  for (int ft = 0; ft < 4; ++ft) {
    accA[ft] = (floatx4){0.f, 0.f, 0.f, 0.f};
    accB[ft] = (floatx4){0.f, 0.f, 0.f, 0.f};
  }
  floatx4 dpA = (floatx4){0.f, 0.f, 0.f, 0.f};
  floatx4 dpB = (floatx4){0.f, 0.f, 0.f, 0.f};

  // prefetch chunk c0: EA lo/hi, EB lo/hi, both mask words
  uint4 pA0 = *(const uint4*)pEA;
  uint4 pA1 = *(const uint4*)(pEA + 16);
  uint4 pB0 = *(const uint4*)pEB;
  uint4 pB1 = *(const uint4*)(pEB + 16);
  unsigned long long pMvA = pM[0];
  unsigned long long pMvB = pM[16];

  for (int cc = c0; cc < cEnd; ++cc) {
    // ---- issue shared B loads for this chunk ----
    half8v b0, b1, b2, b3, b4, b5, b6, b7;
    b0 = *(const half8v*)pB;                     b1 = *(const half8v*)(pB + 512);
    b2 = *(const half8v*)(pB + (64 << 10));      b3 = *(const half8v*)(pB + (64 << 10) + 512);
    b4 = *(const half8v*)(pB + (128 << 10));     b5 = *(const half8v*)(pB + (128 << 10) + 512);
    b6 = *(const half8v*)(pB + (192 << 10));     b7 = *(const half8v*)(pB + (192 << 10) + 512);
    pB += 1024;
    // ---- stash current E/mask, prefetch next ----
    const uint4 eA0 = pA0, eA1 = pA1, eB0 = pB0, eB1 = pB1;
    const unsigned long long mbA = pMvA, mbB = pMvB;
    pEA += 32; pEB += 32; pM += N_NODES;
    if (cc + 1 < cEnd) {
      pA0 = *(const uint4*)pEA;
      pA1 = *(const uint4*)(pEA + 16);
      pB0 = *(const uint4*)pEB;
      pB1 = *(const uint4*)(pEB + 16);
      pMvA = pM[0];
      pMvB = pM[16];
    }
    const unsigned ea_lo[4] = {eA0.x, eA0.y, eA0.z, eA0.w};
    const unsigned eb_lo[4] = {eB0.x, eB0.y, eB0.z, eB0.w};
    const unsigned ea_hi[4] = {eA1.x, eA1.y, eA1.z, eA1.w};
    const unsigned eb_hi[4] = {eB1.x, eB1.y, eB1.z, eB1.w};
    // ---- tile A: w-compute + MFMAs ----
    {
      const unsigned mlo = (unsigned)(mbA >> q8);
      const unsigned mhi = (unsigned)(mbA >> (32 + q8));
      H8U4 a0, a1;
      #pragma unroll
      for (int p = 0; p < 4; ++p) {
        const half2v w2 = __builtin_elementwise_max(c1A * asH2(ea_lo[p]),
                                                    c2A * asH2(eb_lo[p]));
        const unsigned tb = mlo >> (2 * p);
        a0.u[p] = asU(w2) & (((tb & 1u) | ((tb & 2u) << 15)) * 0xFFFFu);
      }
      #pragma unroll
      for (int p = 0; p < 4; ++p) {
        const half2v w2 = __builtin_elementwise_max(c1A * asH2(ea_hi[p]),
                                                    c2A * asH2(eb_hi[p]));
        const unsigned tb = mhi >> (2 * p);
        a1.u[p] = asU(w2) & (((tb & 1u) | ((tb & 2u) << 15)) * 0xFFFFu);
      }
      dpA = __builtin_amdgcn_mfma_f32_16x16x32_f16(a0.v, ones, dpA, 0, 0, 0);
      dpA = __builtin_amdgcn_mfma_f32_16x16x32_f16(a1.v, ones, dpA, 0, 0, 0);
      accA[0] = __builtin_amdgcn_mfma_f32_16x16x32_f16(a0.v, b0, accA[0], 0, 0, 0);
      accA[0] = __builtin_amdgcn_mfma_f32_16x16x32_f16(a1.v, b1, accA[0], 0, 0, 0);
      accA[1] = __builtin_amdgcn_mfma_f32_16x16x32_f16(a0.v, b2, accA[1], 0, 0, 0);
      accA[1] = __builtin_amdgcn_mfma_f32_16x16x32_f16(a1.v, b3, accA[1], 0, 0, 0);
      accA[2] = __builtin_amdgcn_mfma_f32_16x16x32_f16(a0.v, b4, accA[2], 0, 0, 0);
      accA[2] = __builtin_amdgcn_mfma_f32_16x16x32_f16(a1.v, b5, accA[2], 0, 0, 0);
      accA[3] = __builtin_amdgcn_mfma_f32_16x16x32_f16(a0.v, b6, accA[3], 0, 0, 0);
      accA[3] = __builtin_amdgcn_mfma_f32_16x16x32_f16(a1.v, b7, accA[3], 0, 0, 0);
    }
    // ---- tile B: w-compute + MFMAs (reuses E regs + B frags) ----
    {
      const unsigned mlo = (unsigned)(mbB >> q8);
      const unsigned mhi = (unsigned)(mbB >> (32 + q8));
      H8U4 a0, a1;
      #pragma unroll
      for (int p = 0; p < 4; ++p) {
        const half2v w2 = __builtin_elementwise_max(c1B * asH2(ea_lo[p]),
                                                    c2B * asH2(eb_lo[p]));
        const unsigned tb = mlo >> (2 * p);
        a0.u[p] = asU(w2) & (((tb & 1u) | ((tb & 2u) << 15)) * 0xFFFFu);
      }
      #pragma unroll
      for (int p = 0; p < 4; ++p) {
        const half2v w2 = __builtin_elementwise_max(c1B * asH2(ea_hi[p]),
                                                    c2B * asH2(eb_hi[p]));
        const unsigned tb = mhi >> (2 * p);
        a1.u[p] = asU(w2) & (((tb & 1u) | ((tb & 2u) << 15)) * 0xFFFFu);
      }
      dpB = __builtin_amdgcn_mfma_f32_16x16x32_f16(a0.v, ones, dpB, 0, 0, 0);
      dpB = __builtin_amdgcn_mfma_f32_16x16x32_f16(a1.v, ones, dpB, 0, 0, 0);
      accB[0] = __builtin_amdgcn_mfma_f32_16x16x32_f16(a0.v, b0, accB[0], 0, 0, 0);
      accB[0] = __builtin_amdgcn_mfma_f32_16x16x32_f16(a1.v, b1, accB[0], 0, 0, 0);
      accB[1] = __builtin_amdgcn_mfma_f32_16x16x32_f16(a0.v, b2, accB[1], 0, 0, 0);
      accB[1] = __builtin_amdgcn_mfma_f32_16x16x32_f16(a1.v, b3, accB[1], 0, 0, 0);
      accB[2] = __builtin_amdgcn_mfma_f32_16x16x32_f16(a0.v, b4, accB[2], 0, 0, 0);
      accB[2] = __builtin_amdgcn_mfma_f32_16x16x32_f16(a1.v, b5, accB[2], 0, 0, 0);
      accB[3] = __builtin_amdgcn_mfma_f32_16x16x32_f16(a0.v, b6, accB[3], 0, 0, 0);
      accB[3] = __builtin_amdgcn_mfma_f32_16x16x32_f16(a1.v, b7, accB[3], 0, 0, 0);
    }
  }

  // ---- phase A epilogue (rows n0..n0+15) ----
  #pragma unroll
  for (int i = 0; i < 16; ++i) lds_acc[w4][lane][i] = accA[i >> 2][i & 3];
  #pragma unroll
  for (int i = 0; i < 4; ++i) lds_acc[w4][lane][16 + i] = dpA[i];
  __syncthreads();
  #pragma unroll
  for (int j = 0; j < 4; ++j) {
    const int sl = 4 * w4 + j;
    float fa = 0.f, dpt = 0.f;
    #pragma unroll
    for (int w2 = 0; w2 < 4; ++w2) {
      fa  += lds_acc[w2][lane][sl];
      dpt += lds_acc[w2][lane][16 + j];
    }
    float v = fa / dpt;
    v = (v > 0.f) ? v : (__expf(v) - 1.f);
    v = (v > 0.f) ? v : (__expf(v) - 1.f);
    out[(size_t)(n0 + quad * 4 + j) * KF + k * 64 + w4 * 16 + row] = v;
  }
  __syncthreads();
  // ---- phase B epilogue (rows n0+16..n0+31) ----
  #pragma unroll
  for (int i = 0; i < 16; ++i) lds_acc[w4][lane][i] = accB[i >> 2][i & 3];
  #pragma unroll
  for (int i = 0; i < 4; ++i) lds_acc[w4][lane][16 + i] = dpB[i];
  __syncthreads();
  #pragma unroll
  for (int j = 0; j < 4; ++j) {
    const int sl = 4 * w4 + j;
    float fa = 0.f, dpt = 0.f;
    #pragma unroll
    for (int w2 = 0; w2 < 4; ++w2) {
      fa  += lds_acc[w2][lane][sl];
      dpt += lds_acc[w2][lane][16 + j];
    }
    float v = fa / dpt;
    v = (v > 0.f) ? v : (__expf(v) - 1.f);
    v = (v > 0.f) ? v : (__expf(v) - 1.f);
    out[(size_t)(n0 + 16 + quad * 4 + j) * KF + k * 64 + w4 * 16 + row] = v;
  }
}

// ---------- launcher ----------
extern "C" void kernel_launch(void* const* d_in, const int* in_sizes, int n_in,
                              void* d_out, int out_size, void* d_ws, size_t ws_size,
                              hipStream_t stream) {
  const float* x    = (const float*)d_in[0];   // (4096,256) fp32
  const float* Ww   = (const float*)d_in[1];   // (512,256)  fp32
  const float* Wb   = (const float*)d_in[2];   // (512,)     fp32
  const float* al   = (const float*)d_in[3];   // (1,8,64)   fp32
  const float* ar   = (const float*)d_in[4];   // (1,8,64)   fp32
  const int*   mask = (const int*)d_in[5];     // (1,4096,4096) int32

  float* out      = (float*)d_out;                    // (4096,512) fp32, 8 MB
  float* out_mask = out + (size_t)N_NODES * KF;       // (1,4096,4096) fp32, 64 MB

  const bool use_ws = (ws_size >= (8u << 20));
  char* scratch = use_ws ? (char*)d_ws : (char*)out_mask;
  unsigned short* xeB  = (unsigned short*)scratch;                 // 4 MB
  float*          hl   = (float*)(scratch + (4u << 20));           // 128 KB
  unsigned*       EA   = (unsigned*)(hl + KH * N_NODES);           // 64 KB
  unsigned*       EB   = EA + KH * 2048;                           // 64 KB
  float*          bmax = (float*)(EB + KH * 2048);                 // 2 KB
  unsigned long long* mbitsT = (unsigned long long*)(scratch + (5u << 20)); // 2 MB
  // top of use: 7 MB

  dim3 ga(N_NODES / 64, KF / 64);
  xe_gemm<<<ga, 256, 0, stream>>>(x, Ww, Wb, al, ar, xeB, hl, EA, EB, bmax);

  if (use_ws) {
    mask_fused<<<64 * 64, 256, 0, stream>>>(mask, out_mask, mbitsT);
    gat_attn<<<128 * KH, 256, 0, stream>>>(mbitsT, hl, bmax, EA, EB, xeB, out);
  } else {
    mask_pack<<<(N_NODES * (size_t)N_NODES) / 256, 256, 0, stream>>>(mask, mbitsT);
    gat_attn<<<128 * KH, 256, 0, stream>>>(mbitsT, hl, bmax, EA, EB, xeB, out);
    mask_copy<<<(N_NODES * (size_t)N_NODES) / (4 * 256), 256, 0, stream>>>(mask, out_mask);
  }
}

// Round 14
// 212.342 us; speedup vs baseline: 1.2156x; 1.2156x over previous
//
#include <hip/hip_runtime.h>
#include <hip/hip_bf16.h>

// Problem constants (GAT_18176301597437)
#define N_NODES 4096
#define F_IN    256
#define KH      8
#define KF      512          // KH*FPH
#define NEG_SLOPE 0.2f
#define EBIAS   4.0f

typedef _Float16 half8v __attribute__((ext_vector_type(8)));   // MFMA f16 A/B
typedef _Float16 half2v __attribute__((ext_vector_type(2)));   // packed f16 pair
typedef __attribute__((ext_vector_type(4))) float floatx4;     // MFMA C/D

union H8U4 { half8v v; unsigned u[4]; };

__device__ __forceinline__ unsigned short f2h(float f) {
    _Float16 h = (_Float16)f;
    unsigned short u; __builtin_memcpy(&u, &h, 2);
    return u;
}
__device__ __forceinline__ half2v asH2(unsigned u) {
    half2v h; __builtin_memcpy(&h, &u, 4);
    return h;
}
__device__ __forceinline__ unsigned asU(half2v h) {
    unsigned u; __builtin_memcpy(&u, &h, 4);
    return u;
}

// ---------- mask_fused (R12 version): fp32 passthrough + transposed bit-pack --
__global__ __launch_bounds__(256) void mask_fused(
    const int* __restrict__ mask, float* __restrict__ outm,
    unsigned long long* __restrict__ bits) {
  const size_t base = (size_t)blockIdx.x * 1024;
  const int tid = threadIdx.x;
  #pragma unroll
  for (int c = 0; c < 4; ++c) {
    const size_t e = base + c * 256 + tid;
    const int v = mask[e];
    outm[e] = v ? 1.f : 0.f;
    const unsigned long long b = __ballot(v != 0);
    if ((tid & 63) == 0) {
      const size_t w = e >> 6;
      bits[(w & 63) * (size_t)N_NODES + (w >> 6)] = b;
    }
  }
}

// ---------- fallback pair (scratch inside out_mask region) ----------
__global__ __launch_bounds__(256) void mask_pack(
    const int* __restrict__ mask, unsigned long long* __restrict__ bits) {
  const size_t idx = (size_t)blockIdx.x * 256 + threadIdx.x;
  const unsigned long long b = __ballot(mask[idx] != 0);
  if ((threadIdx.x & 63) == 0) {
    const size_t w = idx >> 6;
    bits[(w & 63) * (size_t)N_NODES + (w >> 6)] = b;
  }
}
__global__ __launch_bounds__(256) void mask_copy(
    const int* __restrict__ mask, float* __restrict__ outm) {
  const size_t i4 = (size_t)blockIdx.x * 256 + threadIdx.x;
  const int4 mv = ((const int4*)mask)[i4];
  float4 o;
  o.x = mv.x ? 1.f : 0.f; o.y = mv.y ? 1.f : 0.f;
  o.z = mv.z ? 1.f : 0.f; o.w = mv.w ? 1.f : 0.f;
  ((float4*)outm)[i4] = o;
}

// ---------- Kernel A: xe-GEMM + fused hl/EA/EB/blockmax epilogue -------------
// xeB tile = (head k, ft, chunk c): 1024 f16 = [h(2)][f(16)][quad(4)][j(8)].
// EA[k][n/2] = packed f16 pair exp(hr-4); EB = exp(0.2*(hr-4)).
__global__ __launch_bounds__(256) void xe_gemm(
    const float* __restrict__ x,
    const float* __restrict__ Ww,
    const float* __restrict__ Wb,
    const float* __restrict__ al,
    const float* __restrict__ ar,
    unsigned short* __restrict__ xeB,
    float* __restrict__ hl,             // [8][4096]
    unsigned* __restrict__ EA,          // [8][2048]
    unsigned* __restrict__ EB,          // [8][2048]
    float* __restrict__ bmax) {         // [8][64]
  __shared__ float As[32][65];
  __shared__ float Bs[32][65];
  __shared__ float redmax[4];
  const int tid = threadIdx.x;
  const int n0 = blockIdx.x * 64;
  const int j0 = blockIdx.y * 64;
  const int lr = tid >> 2;
  const int lc = (tid & 3) * 8;
  const int ty = tid >> 4;
  const int tx = tid & 15;
  float c[4][4];
  #pragma unroll
  for (int i = 0; i < 4; ++i)
    #pragma unroll
    for (int j = 0; j < 4; ++j) c[i][j] = 0.f;

  for (int f0 = 0; f0 < F_IN; f0 += 32) {
    const float* ap = x  + (size_t)(n0 + lr) * F_IN + f0 + lc;
    const float* bp = Ww + (size_t)(j0 + lr) * F_IN + f0 + lc;
    const float4 a0 = *(const float4*)ap;
    const float4 a1 = *(const float4*)(ap + 4);
    const float4 b0 = *(const float4*)bp;
    const float4 b1 = *(const float4*)(bp + 4);
    __syncthreads();
    As[lc + 0][lr] = a0.x; As[lc + 1][lr] = a0.y;
    As[lc + 2][lr] = a0.z; As[lc + 3][lr] = a0.w;
    As[lc + 4][lr] = a1.x; As[lc + 5][lr] = a1.y;
    As[lc + 6][lr] = a1.z; As[lc + 7][lr] = a1.w;
    Bs[lc + 0][lr] = b0.x; Bs[lc + 1][lr] = b0.y;
    Bs[lc + 2][lr] = b0.z; Bs[lc + 3][lr] = b0.w;
    Bs[lc + 4][lr] = b1.x; Bs[lc + 5][lr] = b1.y;
    Bs[lc + 6][lr] = b1.z; Bs[lc + 7][lr] = b1.w;
    __syncthreads();
    #pragma unroll
    for (int kk = 0; kk < 32; ++kk) {
      const float4 av = *(const float4*)&As[kk][ty * 4];
      const float4 bv = *(const float4*)&Bs[kk][tx * 4];
      const float a4[4] = {av.x, av.y, av.z, av.w};
      const float b4[4] = {bv.x, bv.y, bv.z, bv.w};
      #pragma unroll
      for (int i = 0; i < 4; ++i)
        #pragma unroll
        for (int j = 0; j < 4; ++j) c[i][j] = fmaf(a4[i], b4[j], c[i][j]);
    }
  }
  const float4 wb4 = *(const float4*)(Wb + j0 + tx * 4);
  const float4 al4 = *(const float4*)(al + j0 + tx * 4);
  const float4 ar4 = *(const float4*)(ar + j0 + tx * 4);
  const float wb[4] = {wb4.x, wb4.y, wb4.z, wb4.w};
  const float alv[4] = {al4.x, al4.y, al4.z, al4.w};
  const float arv[4] = {ar4.x, ar4.y, ar4.z, ar4.w};
  float v[4][4];
  float pl[4], pr[4];
  #pragma unroll
  for (int i = 0; i < 4; ++i) {
    float sl = 0.f, sr = 0.f;
    #pragma unroll
    for (int j = 0; j < 4; ++j) {
      v[i][j] = c[i][j] + wb[j];
      sl = fmaf(v[i][j], alv[j], sl);
      sr = fmaf(v[i][j], arv[j], sr);
    }
    pl[i] = sl; pr[i] = sr;
  }
  {
    const int k   = blockIdx.y;
    const int ft  = tx >> 2;
    const int fb  = (tx & 3) * 4;
    const int cc  = blockIdx.x;
    const int h_  = ty >> 3;
    const int qd  = (ty >> 1) & 3;
    const int jj0 = (ty & 1) * 4;
    unsigned short* tile = xeB + ((((size_t)(k * 4 + ft)) * 64 + cc) << 10)
                         + h_ * 512 + qd * 8 + jj0;
    #pragma unroll
    for (int j = 0; j < 4; ++j) {
      ushort4 pk;
      pk.x = f2h(v[0][j]); pk.y = f2h(v[1][j]);
      pk.z = f2h(v[2][j]); pk.w = f2h(v[3][j]);
      *(ushort4*)(tile + (fb + j) * 32) = pk;
    }
  }
  #pragma unroll
  for (int off = 8; off > 0; off >>= 1) {
    #pragma unroll
    for (int i = 0; i < 4; ++i) {
      pl[i] += __shfl_down(pl[i], off);
      pr[i] += __shfl_down(pr[i], off);
    }
  }
  if (tx == 0) {
    const int k = blockIdx.y;
    float4 o0 = {pl[0], pl[1], pl[2], pl[3]};
    *(float4*)(hl + k * N_NODES + n0 + ty * 4) = o0;
    unsigned short e1[4], e2[4];
    #pragma unroll
    for (int i = 0; i < 4; ++i) {
      e1[i] = f2h(__expf(pr[i] - EBIAS));
      e2[i] = f2h(__expf(NEG_SLOPE * (pr[i] - EBIAS)));
    }
    uint2 wa, wbv;
    wa.x  = (unsigned)e1[0] | ((unsigned)e1[1] << 16);
    wa.y  = (unsigned)e1[2] | ((unsigned)e1[3] << 16);
    wbv.x = (unsigned)e2[0] | ((unsigned)e2[1] << 16);
    wbv.y = (unsigned)e2[2] | ((unsigned)e2[3] << 16);
    *(uint2*)(EA + k * 2048 + ((n0 + ty * 4) >> 1)) = wa;
    *(uint2*)(EB + k * 2048 + ((n0 + ty * 4) >> 1)) = wbv;
  }
  float bm = (tx == 0)
      ? fmaxf(fmaxf(pr[0], pr[1]), fmaxf(pr[2], pr[3])) : -1e30f;
  bm = fmaxf(bm, __shfl_xor(bm, 16));
  bm = fmaxf(bm, __shfl_xor(bm, 32));
  if ((tid & 63) == 0) redmax[tid >> 6] = bm;
  __syncthreads();
  if (tid == 0) {
    bmax[blockIdx.y * 64 + blockIdx.x] =
        fmaxf(fmaxf(redmax[0], redmax[1]), fmaxf(redmax[2], redmax[3]));
  }
}

// ---------- Kernel D: fused attention, 32 rows/block, shared B, no spills ----
// Block = 256 thr = 4 waves = (32-row group, head); wave = 16 m-chunks.
// Two 16-row MFMA tiles share each chunk's B and E loads. launch_bounds(256,2)
// raises the VGPR cap to 256 so the ~140-reg live set does NOT spill (R13's
// (256,4)=128 cap caused ~120 MB of scratch traffic).
__global__ __launch_bounds__(256, 2) void gat_attn(
    const unsigned long long* __restrict__ mbitsT,   // [64 c][4096 n]
    const float* __restrict__ hl,
    const float* __restrict__ bmax,                  // [8][64]
    const unsigned* __restrict__ EA,                 // [8][2048] f16 pairs
    const unsigned* __restrict__ EB,
    const unsigned short* __restrict__ xeB,          // f16 frag tiles
    float* __restrict__ out) {
  __shared__ float lds_acc[4][64][20];   // 20 KB (reused for both phases)
  const int t = threadIdx.x;
  const int w4 = t >> 6;                // wave 0..3 = m-quarter
  const int lane = t & 63;
  const int k  = blockIdx.x >> 7;       // same-k grouping for L2 locality
  const int rg = blockIdx.x & 127;
  const int n0 = rg * 32;
  const int row = lane & 15;
  const int quad = lane >> 4;
  const int q8 = quad * 8;

  float hm = bmax[k * 64 + lane];
  #pragma unroll
  for (int o = 1; o < 64; o <<= 1) hm = fmaxf(hm, __shfl_xor(hm, o));

  const float* hlp = hl + k * N_NODES + n0 + row;
  const float hlA = hlp[0];
  const float hlB = hlp[16];
  const float sA = hlA + hm;
  const float MA = fmaxf(sA, NEG_SLOPE * sA);
  const float sB = hlB + hm;
  const float MB = fmaxf(sB, NEG_SLOPE * sB);
  const float c1Af = __expf(hlA + EBIAS - MA);
  const float c2Af = __expf(NEG_SLOPE * (hlA + EBIAS) - MA);
  const float c1Bf = __expf(hlB + EBIAS - MB);
  const float c2Bf = __expf(NEG_SLOPE * (hlB + EBIAS) - MB);
  const half2v c1A = {(_Float16)c1Af, (_Float16)c1Af};
  const half2v c2A = {(_Float16)c2Af, (_Float16)c2Af};
  const half2v c1B = {(_Float16)c1Bf, (_Float16)c1Bf};
  const half2v c2B = {(_Float16)c2Bf, (_Float16)c2Bf};

  const int c0 = w4 * 16;
  const int cEnd = c0 + 16;

  // running pointers
  const unsigned* pEA = EA + k * 2048 + c0 * 32 + quad * 4;
  const unsigned* pEB = EB + k * 2048 + c0 * 32 + quad * 4;
  const unsigned long long* pM = mbitsT + (size_t)c0 * N_NODES + n0 + row;
  const unsigned short* pB = xeB + (((size_t)k * 4) << 16)
                           + ((size_t)c0 << 10) + row * 32 + q8;

  half8v ones;
  #pragma unroll
  for (int i = 0; i < 8; ++i) ones[i] = (_Float16)1.0f;

  floatx4 accA[4], accB[4];
  #pragma unroll
  for (int ft = 0; ft < 4; ++ft) {
    accA[ft] = (floatx4){0.f, 0.f, 0.f, 0.f};
    accB[ft] = (floatx4){0.f, 0.f, 0.f, 0.f};
  }
  floatx4 dpA = (floatx4){0.f, 0.f, 0.f, 0.f};
  floatx4 dpB = (floatx4){0.f, 0.f, 0.f, 0.f};

  // prefetch chunk c0: EA lo/hi, EB lo/hi, both mask words
  uint4 pA0 = *(const uint4*)pEA;
  uint4 pA1 = *(const uint4*)(pEA + 16);
  uint4 pB0 = *(const uint4*)pEB;
  uint4 pB1 = *(const uint4*)(pEB + 16);
  unsigned long long pMvA = pM[0];
  unsigned long long pMvB = pM[16];

  for (int cc = c0; cc < cEnd; ++cc) {
    // ---- issue shared B loads for this chunk ----
    half8v b0, b1, b2, b3, b4, b5, b6, b7;
    b0 = *(const half8v*)pB;                     b1 = *(const half8v*)(pB + 512);
    b2 = *(const half8v*)(pB + (64 << 10));      b3 = *(const half8v*)(pB + (64 << 10) + 512);
    b4 = *(const half8v*)(pB + (128 << 10));     b5 = *(const half8v*)(pB + (128 << 10) + 512);
    b6 = *(const half8v*)(pB + (192 << 10));     b7 = *(const half8v*)(pB + (192 << 10) + 512);
    pB += 1024;
    // ---- stash current E/mask, prefetch next ----
    const uint4 eA0 = pA0, eA1 = pA1, eB0 = pB0, eB1 = pB1;
    const unsigned long long mbA = pMvA, mbB = pMvB;
    pEA += 32; pEB += 32; pM += N_NODES;
    if (cc + 1 < cEnd) {
      pA0 = *(const uint4*)pEA;
      pA1 = *(const uint4*)(pEA + 16);
      pB0 = *(const uint4*)pEB;
      pB1 = *(const uint4*)(pEB + 16);
      pMvA = pM[0];
      pMvB = pM[16];
    }
    const unsigned ea_lo[4] = {eA0.x, eA0.y, eA0.z, eA0.w};
    const unsigned eb_lo[4] = {eB0.x, eB0.y, eB0.z, eB0.w};
    const unsigned ea_hi[4] = {eA1.x, eA1.y, eA1.z, eA1.w};
    const unsigned eb_hi[4] = {eB1.x, eB1.y, eB1.z, eB1.w};
    // ---- tile A: w-compute + MFMAs ----
    {
      const unsigned mlo = (unsigned)(mbA >> q8);
      const unsigned mhi = (unsigned)(mbA >> (32 + q8));
      H8U4 a0, a1;
      #pragma unroll
      for (int p = 0; p < 4; ++p) {
        const half2v w2 = __builtin_elementwise_max(c1A * asH2(ea_lo[p]),
                                                    c2A * asH2(eb_lo[p]));
        const unsigned tb = mlo >> (2 * p);
        a0.u[p] = asU(w2) & (((tb & 1u) | ((tb & 2u) << 15)) * 0xFFFFu);
      }
      #pragma unroll
      for (int p = 0; p < 4; ++p) {
        const half2v w2 = __builtin_elementwise_max(c1A * asH2(ea_hi[p]),
                                                    c2A * asH2(eb_hi[p]));
        const unsigned tb = mhi >> (2 * p);
        a1.u[p] = asU(w2) & (((tb & 1u) | ((tb & 2u) << 15)) * 0xFFFFu);
      }
      dpA = __builtin_amdgcn_mfma_f32_16x16x32_f16(a0.v, ones, dpA, 0, 0, 0);
      dpA = __builtin_amdgcn_mfma_f32_16x16x32_f16(a1.v, ones, dpA, 0, 0, 0);
      accA[0] = __builtin_amdgcn_mfma_f32_16x16x32_f16(a0.v, b0, accA[0], 0, 0, 0);
      accA[0] = __builtin_amdgcn_mfma_f32_16x16x32_f16(a1.v, b1, accA[0], 0, 0, 0);
      accA[1] = __builtin_amdgcn_mfma_f32_16x16x32_f16(a0.v, b2, accA[1], 0, 0, 0);
      accA[1] = __builtin_amdgcn_mfma_f32_16x16x32_f16(a1.v, b3, accA[1], 0, 0, 0);
      accA[2] = __builtin_amdgcn_mfma_f32_16x16x32_f16(a0.v, b4, accA[2], 0, 0, 0);
      accA[2] = __builtin_amdgcn_mfma_f32_16x16x32_f16(a1.v, b5, accA[2], 0, 0, 0);
      accA[3] = __builtin_amdgcn_mfma_f32_16x16x32_f16(a0.v, b6, accA[3], 0, 0, 0);
      accA[3] = __builtin_amdgcn_mfma_f32_16x16x32_f16(a1.v, b7, accA[3], 0, 0, 0);
    }
    // ---- tile B: w-compute + MFMAs (reuses E regs + B frags) ----
    {
      const unsigned mlo = (unsigned)(mbB >> q8);
      const unsigned mhi = (unsigned)(mbB >> (32 + q8));
      H8U4 a0, a1;
      #pragma unroll
      for (int p = 0; p < 4; ++p) {
        const half2v w2 = __builtin_elementwise_max(c1B * asH2(ea_lo[p]),
                                                    c2B * asH2(eb_lo[p]));
        const unsigned tb = mlo >> (2 * p);
        a0.u[p] = asU(w2) & (((tb & 1u) | ((tb & 2u) << 15)) * 0xFFFFu);
      }
      #pragma unroll
      for (int p = 0; p < 4; ++p) {
        const half2v w2 = __builtin_elementwise_max(c1B * asH2(ea_hi[p]),
                                                    c2B * asH2(eb_hi[p]));
        const unsigned tb = mhi >> (2 * p);
        a1.u[p] = asU(w2) & (((tb & 1u) | ((tb & 2u) << 15)) * 0xFFFFu);
      }
      dpB = __builtin_amdgcn_mfma_f32_16x16x32_f16(a0.v, ones, dpB, 0, 0, 0);
      dpB = __builtin_amdgcn_mfma_f32_16x16x32_f16(a1.v, ones, dpB, 0, 0, 0);
      accB[0] = __builtin_amdgcn_mfma_f32_16x16x32_f16(a0.v, b0, accB[0], 0, 0, 0);
      accB[0] = __builtin_amdgcn_mfma_f32_16x16x32_f16(a1.v, b1, accB[0], 0, 0, 0);
      accB[1] = __builtin_amdgcn_mfma_f32_16x16x32_f16(a0.v, b2, accB[1], 0, 0, 0);
      accB[1] = __builtin_amdgcn_mfma_f32_16x16x32_f16(a1.v, b3, accB[1], 0, 0, 0);
      accB[2] = __builtin_amdgcn_mfma_f32_16x16x32_f16(a0.v, b4, accB[2], 0, 0, 0);
      accB[2] = __builtin_amdgcn_mfma_f32_16x16x32_f16(a1.v, b5, accB[2], 0, 0, 0);
      accB[3] = __builtin_amdgcn_mfma_f32_16x16x32_f16(a0.v, b6, accB[3], 0, 0, 0);
      accB[3] = __builtin_amdgcn_mfma_f32_16x16x32_f16(a1.v, b7, accB[3], 0, 0, 0);
    }
  }

  // ---- phase A epilogue (rows n0..n0+15) ----
  #pragma unroll
  for (int i = 0; i < 16; ++i) lds_acc[w4][lane][i] = accA[i >> 2][i & 3];
  #pragma unroll
  for (int i = 0; i < 4; ++i) lds_acc[w4][lane][16 + i] = dpA[i];
  __syncthreads();
  #pragma unroll
  for (int j = 0; j < 4; ++j) {
    const int sl = 4 * w4 + j;
    float fa = 0.f, dpt = 0.f;
    #pragma unroll
    for (int w2 = 0; w2 < 4; ++w2) {
      fa  += lds_acc[w2][lane][sl];
      dpt += lds_acc[w2][lane][16 + j];
    }
    float v = fa / dpt;
    v = (v > 0.f) ? v : (__expf(v) - 1.f);
    v = (v > 0.f) ? v : (__expf(v) - 1.f);
    out[(size_t)(n0 + quad * 4 + j) * KF + k * 64 + w4 * 16 + row] = v;
  }
  __syncthreads();
  // ---- phase B epilogue (rows n0+16..n0+31) ----
  #pragma unroll
  for (int i = 0; i < 16; ++i) lds_acc[w4][lane][i] = accB[i >> 2][i & 3];
  #pragma unroll
  for (int i = 0; i < 4; ++i) lds_acc[w4][lane][16 + i] = dpB[i];
  __syncthreads();
  #pragma unroll
  for (int j = 0; j < 4; ++j) {
    const int sl = 4 * w4 + j;
    float fa = 0.f, dpt = 0.f;
    #pragma unroll
    for (int w2 = 0; w2 < 4; ++w2) {
      fa  += lds_acc[w2][lane][sl];
      dpt += lds_acc[w2][lane][16 + j];
    }
    float v = fa / dpt;
    v = (v > 0.f) ? v : (__expf(v) - 1.f);
    v = (v > 0.f) ? v : (__expf(v) - 1.f);
    out[(size_t)(n0 + 16 + quad * 4 + j) * KF + k * 64 + w4 * 16 + row] = v;
  }
}

// ---------- launcher ----------
extern "C" void kernel_launch(void* const* d_in, const int* in_sizes, int n_in,
                              void* d_out, int out_size, void* d_ws, size_t ws_size,
                              hipStream_t stream) {
  const float* x    = (const float*)d_in[0];   // (4096,256) fp32
  const float* Ww   = (const float*)d_in[1];   // (512,256)  fp32
  const float* Wb   = (const float*)d_in[2];   // (512,)     fp32
  const float* al   = (const float*)d_in[3];   // (1,8,64)   fp32
  const float* ar   = (const float*)d_in[4];   // (1,8,64)   fp32
  const int*   mask = (const int*)d_in[5];     // (1,4096,4096) int32

  float* out      = (float*)d_out;                    // (4096,512) fp32, 8 MB
  float* out_mask = out + (size_t)N_NODES * KF;       // (1,4096,4096) fp32, 64 MB

  const bool use_ws = (ws_size >= (8u << 20));
  char* scratch = use_ws ? (char*)d_ws : (char*)out_mask;
  unsigned short* xeB  = (unsigned short*)scratch;                 // 4 MB
  float*          hl   = (float*)(scratch + (4u << 20));           // 128 KB
  unsigned*       EA   = (unsigned*)(hl + KH * N_NODES);           // 64 KB
  unsigned*       EB   = EA + KH * 2048;                           // 64 KB
  float*          bmax = (float*)(EB + KH * 2048);                 // 2 KB
  unsigned long long* mbitsT = (unsigned long long*)(scratch + (5u << 20)); // 2 MB
  // top of use: 7 MB

  dim3 ga(N_NODES / 64, KF / 64);
  xe_gemm<<<ga, 256, 0, stream>>>(x, Ww, Wb, al, ar, xeB, hl, EA, EB, bmax);

  if (use_ws) {
    mask_fused<<<(N_NODES * (size_t)N_NODES) / 1024, 256, 0, stream>>>(
        mask, out_mask, mbitsT);
    gat_attn<<<128 * KH, 256, 0, stream>>>(mbitsT, hl, bmax, EA, EB, xeB, out);
  } else {
    mask_pack<<<(N_NODES * (size_t)N_NODES) / 256, 256, 0, stream>>>(mask, mbitsT);
    gat_attn<<<128 * KH, 256, 0, stream>>>(mbitsT, hl, bmax, EA, EB, xeB, out);
    mask_copy<<<(N_NODES * (size_t)N_NODES) / (4 * 256), 256, 0, stream>>>(mask, out_mask);
  }
}

// Round 15
// 203.694 us; speedup vs baseline: 1.2672x; 1.0425x over previous
//
#include <hip/hip_runtime.h>
#include <hip/hip_bf16.h>

// Problem constants (GAT_18176301597437)
#define N_NODES 4096
#define F_IN    256
#define KH      8
#define KF      512          // KH*FPH
#define NEG_SLOPE 0.2f
#define EBIAS   4.0f

typedef _Float16 half8v __attribute__((ext_vector_type(8)));   // MFMA f16 A/B
typedef _Float16 half2v __attribute__((ext_vector_type(2)));   // packed f16 pair
typedef __attribute__((ext_vector_type(4))) float floatx4;     // MFMA C/D

union H8U4 { half8v v; unsigned u[4]; };

__device__ __forceinline__ unsigned short f2h(float f) {
    _Float16 h = (_Float16)f;
    unsigned short u; __builtin_memcpy(&u, &h, 2);
    return u;
}
__device__ __forceinline__ half2v asH2(unsigned u) {
    half2v h; __builtin_memcpy(&h, &u, 4);
    return h;
}
__device__ __forceinline__ unsigned asU(half2v h) {
    unsigned u; __builtin_memcpy(&u, &h, 4);
    return u;
}

// ---------- mask_fused v3: int4 loads, float4 stores, shfl-OR bit pack -------
// Thread t4 handles elements 4*t4..4*t4+3. Word for 64 consecutive elements is
// assembled from 16 consecutive lanes' nibbles via 64-bit xor-shuffle OR-tree.
// bits layout: word index = c*4096 + n  (e = n*4096 + c*64 + bit).
__global__ __launch_bounds__(256) void mask_fused(
    const int* __restrict__ mask, float* __restrict__ outm,
    unsigned long long* __restrict__ bits) {
  const int tid = threadIdx.x;
  const size_t t4 = (size_t)blockIdx.x * 256 + tid;     // int4 index
  const int4 mv = ((const int4*)mask)[t4];
  float4 o;
  o.x = mv.x ? 1.f : 0.f; o.y = mv.y ? 1.f : 0.f;
  o.z = mv.z ? 1.f : 0.f; o.w = mv.w ? 1.f : 0.f;
  ((float4*)outm)[t4] = o;
  const unsigned nib = (mv.x ? 1u : 0u) | (mv.y ? 2u : 0u) |
                       (mv.z ? 4u : 0u) | (mv.w ? 8u : 0u);
  unsigned long long wv = (unsigned long long)nib << (4 * (tid & 15));
  wv |= __shfl_xor(wv, 1);
  wv |= __shfl_xor(wv, 2);
  wv |= __shfl_xor(wv, 4);
  wv |= __shfl_xor(wv, 8);
  if ((tid & 15) == 0) {
    const size_t e0 = t4 << 2;            // first element of this 64-group
    const size_t n = e0 >> 12;
    const size_t c = (e0 & 4095) >> 6;
    bits[c * N_NODES + n] = wv;
  }
}

// ---------- fallback pair (scratch inside out_mask region) ----------
__global__ __launch_bounds__(256) void mask_pack(
    const int* __restrict__ mask, unsigned long long* __restrict__ bits) {
  const size_t idx = (size_t)blockIdx.x * 256 + threadIdx.x;
  const unsigned long long b = __ballot(mask[idx] != 0);
  if ((threadIdx.x & 63) == 0) {
    const size_t w = idx >> 6;
    bits[(w & 63) * (size_t)N_NODES + (w >> 6)] = b;
  }
}
__global__ __launch_bounds__(256) void mask_copy(
    const int* __restrict__ mask, float* __restrict__ outm) {
  const size_t i4 = (size_t)blockIdx.x * 256 + threadIdx.x;
  const int4 mv = ((const int4*)mask)[i4];
  float4 o;
  o.x = mv.x ? 1.f : 0.f; o.y = mv.y ? 1.f : 0.f;
  o.z = mv.z ? 1.f : 0.f; o.w = mv.w ? 1.f : 0.f;
  ((float4*)outm)[i4] = o;
}

// ---------- Kernel A: xe-GEMM + fused hl/EA/EB/blockmax epilogue -------------
// xeB tile = (head k, ft, chunk c): 1024 f16 = [h(2)][f(16)][quad(4)][j(8)].
// EA[k][n/2] = packed f16 pair exp(hr-4); EB = exp(0.2*(hr-4)).
__global__ __launch_bounds__(256) void xe_gemm(
    const float* __restrict__ x,
    const float* __restrict__ Ww,
    const float* __restrict__ Wb,
    const float* __restrict__ al,
    const float* __restrict__ ar,
    unsigned short* __restrict__ xeB,
    float* __restrict__ hl,             // [8][4096]
    unsigned* __restrict__ EA,          // [8][2048]
    unsigned* __restrict__ EB,          // [8][2048]
    float* __restrict__ bmax) {         // [8][64]
  __shared__ float As[32][65];
  __shared__ float Bs[32][65];
  __shared__ float redmax[4];
  const int tid = threadIdx.x;
  const int n0 = blockIdx.x * 64;
  const int j0 = blockIdx.y * 64;
  const int lr = tid >> 2;
  const int lc = (tid & 3) * 8;
  const int ty = tid >> 4;
  const int tx = tid & 15;
  float c[4][4];
  #pragma unroll
  for (int i = 0; i < 4; ++i)
    #pragma unroll
    for (int j = 0; j < 4; ++j) c[i][j] = 0.f;

  for (int f0 = 0; f0 < F_IN; f0 += 32) {
    const float* ap = x  + (size_t)(n0 + lr) * F_IN + f0 + lc;
    const float* bp = Ww + (size_t)(j0 + lr) * F_IN + f0 + lc;
    const float4 a0 = *(const float4*)ap;
    const float4 a1 = *(const float4*)(ap + 4);
    const float4 b0 = *(const float4*)bp;
    const float4 b1 = *(const float4*)(bp + 4);
    __syncthreads();
    As[lc + 0][lr] = a0.x; As[lc + 1][lr] = a0.y;
    As[lc + 2][lr] = a0.z; As[lc + 3][lr] = a0.w;
    As[lc + 4][lr] = a1.x; As[lc + 5][lr] = a1.y;
    As[lc + 6][lr] = a1.z; As[lc + 7][lr] = a1.w;
    Bs[lc + 0][lr] = b0.x; Bs[lc + 1][lr] = b0.y;
    Bs[lc + 2][lr] = b0.z; Bs[lc + 3][lr] = b0.w;
    Bs[lc + 4][lr] = b1.x; Bs[lc + 5][lr] = b1.y;
    Bs[lc + 6][lr] = b1.z; Bs[lc + 7][lr] = b1.w;
    __syncthreads();
    #pragma unroll
    for (int kk = 0; kk < 32; ++kk) {
      const float4 av = *(const float4*)&As[kk][ty * 4];
      const float4 bv = *(const float4*)&Bs[kk][tx * 4];
      const float a4[4] = {av.x, av.y, av.z, av.w};
      const float b4[4] = {bv.x, bv.y, bv.z, bv.w};
      #pragma unroll
      for (int i = 0; i < 4; ++i)
        #pragma unroll
        for (int j = 0; j < 4; ++j) c[i][j] = fmaf(a4[i], b4[j], c[i][j]);
    }
  }
  const float4 wb4 = *(const float4*)(Wb + j0 + tx * 4);
  const float4 al4 = *(const float4*)(al + j0 + tx * 4);
  const float4 ar4 = *(const float4*)(ar + j0 + tx * 4);
  const float wb[4] = {wb4.x, wb4.y, wb4.z, wb4.w};
  const float alv[4] = {al4.x, al4.y, al4.z, al4.w};
  const float arv[4] = {ar4.x, ar4.y, ar4.z, ar4.w};
  float v[4][4];
  float pl[4], pr[4];
  #pragma unroll
  for (int i = 0; i < 4; ++i) {
    float sl = 0.f, sr = 0.f;
    #pragma unroll
    for (int j = 0; j < 4; ++j) {
      v[i][j] = c[i][j] + wb[j];
      sl = fmaf(v[i][j], alv[j], sl);
      sr = fmaf(v[i][j], arv[j], sr);
    }
    pl[i] = sl; pr[i] = sr;
  }
  {
    const int k   = blockIdx.y;
    const int ft  = tx >> 2;
    const int fb  = (tx & 3) * 4;
    const int cc  = blockIdx.x;
    const int h_  = ty >> 3;
    const int qd  = (ty >> 1) & 3;
    const int jj0 = (ty & 1) * 4;
    unsigned short* tile = xeB + ((((size_t)(k * 4 + ft)) * 64 + cc) << 10)
                         + h_ * 512 + qd * 8 + jj0;
    #pragma unroll
    for (int j = 0; j < 4; ++j) {
      ushort4 pk;
      pk.x = f2h(v[0][j]); pk.y = f2h(v[1][j]);
      pk.z = f2h(v[2][j]); pk.w = f2h(v[3][j]);
      *(ushort4*)(tile + (fb + j) * 32) = pk;
    }
  }
  #pragma unroll
  for (int off = 8; off > 0; off >>= 1) {
    #pragma unroll
    for (int i = 0; i < 4; ++i) {
      pl[i] += __shfl_down(pl[i], off);
      pr[i] += __shfl_down(pr[i], off);
    }
  }
  if (tx == 0) {
    const int k = blockIdx.y;
    float4 o0 = {pl[0], pl[1], pl[2], pl[3]};
    *(float4*)(hl + k * N_NODES + n0 + ty * 4) = o0;
    unsigned short e1[4], e2[4];
    #pragma unroll
    for (int i = 0; i < 4; ++i) {
      e1[i] = f2h(__expf(pr[i] - EBIAS));
      e2[i] = f2h(__expf(NEG_SLOPE * (pr[i] - EBIAS)));
    }
    uint2 wa, wbv;
    wa.x  = (unsigned)e1[0] | ((unsigned)e1[1] << 16);
    wa.y  = (unsigned)e1[2] | ((unsigned)e1[3] << 16);
    wbv.x = (unsigned)e2[0] | ((unsigned)e2[1] << 16);
    wbv.y = (unsigned)e2[2] | ((unsigned)e2[3] << 16);
    *(uint2*)(EA + k * 2048 + ((n0 + ty * 4) >> 1)) = wa;
    *(uint2*)(EB + k * 2048 + ((n0 + ty * 4) >> 1)) = wbv;
  }
  float bm = (tx == 0)
      ? fmaxf(fmaxf(pr[0], pr[1]), fmaxf(pr[2], pr[3])) : -1e30f;
  bm = fmaxf(bm, __shfl_xor(bm, 16));
  bm = fmaxf(bm, __shfl_xor(bm, 32));
  if ((tid & 63) == 0) redmax[tid >> 6] = bm;
  __syncthreads();
  if (tid == 0) {
    bmax[blockIdx.y * 64 + blockIdx.x] =
        fmaxf(fmaxf(redmax[0], redmax[1]), fmaxf(redmax[2], redmax[3]));
  }
}

// ---------- Kernel D: fused attention, 32 rows/block, XCD-pinned heads -------
// Block = 256 thr = 4 waves = (32-row group, head); wave = 16 m-chunks.
// k = blockIdx & 7: workgroup->XCD round-robin pins head k's 128 blocks to one
// XCD, so the per-XCD L2 working set is one 512 KB head tile + 2 MB mask bits
// (fits 4 MiB L2; R14's k=blockIdx>>7 put all 8 heads on every XCD -> thrash,
// FETCH 18 MB vs 6.5 MB read-set).
__global__ __launch_bounds__(256, 2) void gat_attn(
    const unsigned long long* __restrict__ mbitsT,   // [64 c][4096 n]
    const float* __restrict__ hl,
    const float* __restrict__ bmax,                  // [8][64]
    const unsigned* __restrict__ EA,                 // [8][2048] f16 pairs
    const unsigned* __restrict__ EB,
    const unsigned short* __restrict__ xeB,          // f16 frag tiles
    float* __restrict__ out) {
  __shared__ float lds_acc[4][64][20];   // 20 KB (reused for both phases)
  const int t = threadIdx.x;
  const int w4 = t >> 6;                // wave 0..3 = m-quarter
  const int lane = t & 63;
  const int k  = blockIdx.x & 7;        // XCD-pinned head
  const int rg = blockIdx.x >> 3;
  const int n0 = rg * 32;
  const int row = lane & 15;
  const int quad = lane >> 4;
  const int q8 = quad * 8;

  float hm = bmax[k * 64 + lane];
  #pragma unroll
  for (int o = 1; o < 64; o <<= 1) hm = fmaxf(hm, __shfl_xor(hm, o));

  const float* hlp = hl + k * N_NODES + n0 + row;
  const float hlA = hlp[0];
  const float hlB = hlp[16];
  const float sA = hlA + hm;
  const float MA = fmaxf(sA, NEG_SLOPE * sA);
  const float sB = hlB + hm;
  const float MB = fmaxf(sB, NEG_SLOPE * sB);
  const float c1Af = __expf(hlA + EBIAS - MA);
  const float c2Af = __expf(NEG_SLOPE * (hlA + EBIAS) - MA);
  const float c1Bf = __expf(hlB + EBIAS - MB);
  const float c2Bf = __expf(NEG_SLOPE * (hlB + EBIAS) - MB);
  const half2v c1A = {(_Float16)c1Af, (_Float16)c1Af};
  const half2v c2A = {(_Float16)c2Af, (_Float16)c2Af};
  const half2v c1B = {(_Float16)c1Bf, (_Float16)c1Bf};
  const half2v c2B = {(_Float16)c2Bf, (_Float16)c2Bf};

  const int c0 = w4 * 16;
  const int cEnd = c0 + 16;

  // running pointers
  const unsigned* pEA = EA + k * 2048 + c0 * 32 + quad * 4;
  const unsigned* pEB = EB + k * 2048 + c0 * 32 + quad * 4;
  const unsigned long long* pM = mbitsT + (size_t)c0 * N_NODES + n0 + row;
  const unsigned short* pB = xeB + (((size_t)k * 4) << 16)
                           + ((size_t)c0 << 10) + row * 32 + q8;

  half8v ones;
  #pragma unroll
  for (int i = 0; i < 8; ++i) ones[i] = (_Float16)1.0f;

  floatx4 accA[4], accB[4];
  #pragma unroll
  for (int ft = 0; ft < 4; ++ft) {
    accA[ft] = (floatx4){0.f, 0.f, 0.f, 0.f};
    accB[ft] = (floatx4){0.f, 0.f, 0.f, 0.f};
  }
  floatx4 dpA = (floatx4){0.f, 0.f, 0.f, 0.f};
  floatx4 dpB = (floatx4){0.f, 0.f, 0.f, 0.f};

  // prefetch chunk c0: EA lo/hi, EB lo/hi, both mask words
  uint4 pA0 = *(const uint4*)pEA;
  uint4 pA1 = *(const uint4*)(pEA + 16);
  uint4 pB0 = *(const uint4*)pEB;
  uint4 pB1 = *(const uint4*)(pEB + 16);
  unsigned long long pMvA = pM[0];
  unsigned long long pMvB = pM[16];

  for (int cc = c0; cc < cEnd; ++cc) {
    // ---- issue shared B loads for this chunk ----
    half8v b0, b1, b2, b3, b4, b5, b6, b7;
    b0 = *(const half8v*)pB;                     b1 = *(const half8v*)(pB + 512);
    b2 = *(const half8v*)(pB + (64 << 10));      b3 = *(const half8v*)(pB + (64 << 10) + 512);
    b4 = *(const half8v*)(pB + (128 << 10));     b5 = *(const half8v*)(pB + (128 << 10) + 512);
    b6 = *(const half8v*)(pB + (192 << 10));     b7 = *(const half8v*)(pB + (192 << 10) + 512);
    pB += 1024;
    // ---- stash current E/mask, prefetch next ----
    const uint4 eA0 = pA0, eA1 = pA1, eB0 = pB0, eB1 = pB1;
    const unsigned long long mbA = pMvA, mbB = pMvB;
    pEA += 32; pEB += 32; pM += N_NODES;
    if (cc + 1 < cEnd) {
      pA0 = *(const uint4*)pEA;
      pA1 = *(const uint4*)(pEA + 16);
      pB0 = *(const uint4*)pEB;
      pB1 = *(const uint4*)(pEB + 16);
      pMvA = pM[0];
      pMvB = pM[16];
    }
    const unsigned ea_lo[4] = {eA0.x, eA0.y, eA0.z, eA0.w};
    const unsigned eb_lo[4] = {eB0.x, eB0.y, eB0.z, eB0.w};
    const unsigned ea_hi[4] = {eA1.x, eA1.y, eA1.z, eA1.w};
    const unsigned eb_hi[4] = {eB1.x, eB1.y, eB1.z, eB1.w};
    // ---- tile A: w-compute + MFMAs ----
    {
      const unsigned mlo = (unsigned)(mbA >> q8);
      const unsigned mhi = (unsigned)(mbA >> (32 + q8));
      H8U4 a0, a1;
      #pragma unroll
      for (int p = 0; p < 4; ++p) {
        const half2v w2 = __builtin_elementwise_max(c1A * asH2(ea_lo[p]),
                                                    c2A * asH2(eb_lo[p]));
        const unsigned tb = mlo >> (2 * p);
        a0.u[p] = asU(w2) & (((tb & 1u) | ((tb & 2u) << 15)) * 0xFFFFu);
      }
      #pragma unroll
      for (int p = 0; p < 4; ++p) {
        const half2v w2 = __builtin_elementwise_max(c1A * asH2(ea_hi[p]),
                                                    c2A * asH2(eb_hi[p]));
        const unsigned tb = mhi >> (2 * p);
        a1.u[p] = asU(w2) & (((tb & 1u) | ((tb & 2u) << 15)) * 0xFFFFu);
      }
      dpA = __builtin_amdgcn_mfma_f32_16x16x32_f16(a0.v, ones, dpA, 0, 0, 0);
      dpA = __builtin_amdgcn_mfma_f32_16x16x32_f16(a1.v, ones, dpA, 0, 0, 0);
      accA[0] = __builtin_amdgcn_mfma_f32_16x16x32_f16(a0.v, b0, accA[0], 0, 0, 0);
      accA[0] = __builtin_amdgcn_mfma_f32_16x16x32_f16(a1.v, b1, accA[0], 0, 0, 0);
      accA[1] = __builtin_amdgcn_mfma_f32_16x16x32_f16(a0.v, b2, accA[1], 0, 0, 0);
      accA[1] = __builtin_amdgcn_mfma_f32_16x16x32_f16(a1.v, b3, accA[1], 0, 0, 0);
      accA[2] = __builtin_amdgcn_mfma_f32_16x16x32_f16(a0.v, b4, accA[2], 0, 0, 0);
      accA[2] = __builtin_amdgcn_mfma_f32_16x16x32_f16(a1.v, b5, accA[2], 0, 0, 0);
      accA[3] = __builtin_amdgcn_mfma_f32_16x16x32_f16(a0.v, b6, accA[3], 0, 0, 0);
      accA[3] = __builtin_amdgcn_mfma_f32_16x16x32_f16(a1.v, b7, accA[3], 0, 0, 0);
    }
    // ---- tile B: w-compute + MFMAs (reuses E regs + B frags) ----
    {
      const unsigned mlo = (unsigned)(mbB >> q8);
      const unsigned mhi = (unsigned)(mbB >> (32 + q8));
      H8U4 a0, a1;
      #pragma unroll
      for (int p = 0; p < 4; ++p) {
        const half2v w2 = __builtin_elementwise_max(c1B * asH2(ea_lo[p]),
                                                    c2B * asH2(eb_lo[p]));
        const unsigned tb = mlo >> (2 * p);
        a0.u[p] = asU(w2) & (((tb & 1u) | ((tb & 2u) << 15)) * 0xFFFFu);
      }
      #pragma unroll
      for (int p = 0; p < 4; ++p) {
        const half2v w2 = __builtin_elementwise_max(c1B * asH2(ea_hi[p]),
                                                    c2B * asH2(eb_hi[p]));
        const unsigned tb = mhi >> (2 * p);
        a1.u[p] = asU(w2) & (((tb & 1u) | ((tb & 2u) << 15)) * 0xFFFFu);
      }
      dpB = __builtin_amdgcn_mfma_f32_16x16x32_f16(a0.v, ones, dpB, 0, 0, 0);
      dpB = __builtin_amdgcn_mfma_f32_16x16x32_f16(a1.v, ones, dpB, 0, 0, 0);
      accB[0] = __builtin_amdgcn_mfma_f32_16x16x32_f16(a0.v, b0, accB[0], 0, 0, 0);
      accB[0] = __builtin_amdgcn_mfma_f32_16x16x32_f16(a1.v, b1, accB[0], 0, 0, 0);
      accB[1] = __builtin_amdgcn_mfma_f32_16x16x32_f16(a0.v, b2, accB[1], 0, 0, 0);
      accB[1] = __builtin_amdgcn_mfma_f32_16x16x32_f16(a1.v, b3, accB[1], 0, 0, 0);
      accB[2] = __builtin_amdgcn_mfma_f32_16x16x32_f16(a0.v, b4, accB[2], 0, 0, 0);
      accB[2] = __builtin_amdgcn_mfma_f32_16x16x32_f16(a1.v, b5, accB[2], 0, 0, 0);
      accB[3] = __builtin_amdgcn_mfma_f32_16x16x32_f16(a0.v, b6, accB[3], 0, 0, 0);
      accB[3] = __builtin_amdgcn_mfma_f32_16x16x32_f16(a1.v, b7, accB[3], 0, 0, 0);
    }
  }

  // ---- phase A epilogue (rows n0..n0+15) ----
  #pragma unroll
  for (int i = 0; i < 16; ++i) lds_acc[w4][lane][i] = accA[i >> 2][i & 3];
  #pragma unroll
  for (int i = 0; i < 4; ++i) lds_acc[w4][lane][16 + i] = dpA[i];
  __syncthreads();
  #pragma unroll
  for (int j = 0; j < 4; ++j) {
    const int sl = 4 * w4 + j;
    float fa = 0.f, dpt = 0.f;
    #pragma unroll
    for (int w2 = 0; w2 < 4; ++w2) {
      fa  += lds_acc[w2][lane][sl];
      dpt += lds_acc[w2][lane][16 + j];
    }
    float v = fa / dpt;
    v = (v > 0.f) ? v : (__expf(v) - 1.f);
    v = (v > 0.f) ? v : (__expf(v) - 1.f);
    out[(size_t)(n0 + quad * 4 + j) * KF + k * 64 + w4 * 16 + row] = v;
  }
  __syncthreads();
  // ---- phase B epilogue (rows n0+16..n0+31) ----
  #pragma unroll
  for (int i = 0; i < 16; ++i) lds_acc[w4][lane][i] = accB[i >> 2][i & 3];
  #pragma unroll
  for (int i = 0; i < 4; ++i) lds_acc[w4][lane][16 + i] = dpB[i];
  __syncthreads();
  #pragma unroll
  for (int j = 0; j < 4; ++j) {
    const int sl = 4 * w4 + j;
    float fa = 0.f, dpt = 0.f;
    #pragma unroll
    for (int w2 = 0; w2 < 4; ++w2) {
      fa  += lds_acc[w2][lane][sl];
      dpt += lds_acc[w2][lane][16 + j];
    }
    float v = fa / dpt;
    v = (v > 0.f) ? v : (__expf(v) - 1.f);
    v = (v > 0.f) ? v : (__expf(v) - 1.f);
    out[(size_t)(n0 + 16 + quad * 4 + j) * KF + k * 64 + w4 * 16 + row] = v;
  }
}

// ---------- launcher ----------
extern "C" void kernel_launch(void* const* d_in, const int* in_sizes, int n_in,
                              void* d_out, int out_size, void* d_ws, size_t ws_size,
                              hipStream_t stream) {
  const float* x    = (const float*)d_in[0];   // (4096,256) fp32
  const float* Ww   = (const float*)d_in[1];   // (512,256)  fp32
  const float* Wb   = (const float*)d_in[2];   // (512,)     fp32
  const float* al   = (const float*)d_in[3];   // (1,8,64)   fp32
  const float* ar   = (const float*)d_in[4];   // (1,8,64)   fp32
  const int*   mask = (const int*)d_in[5];     // (1,4096,4096) int32

  float* out      = (float*)d_out;                    // (4096,512) fp32, 8 MB
  float* out_mask = out + (size_t)N_NODES * KF;       // (1,4096,4096) fp32, 64 MB

  const bool use_ws = (ws_size >= (8u << 20));
  char* scratch = use_ws ? (char*)d_ws : (char*)out_mask;
  unsigned short* xeB  = (unsigned short*)scratch;                 // 4 MB
  float*          hl   = (float*)(scratch + (4u << 20));           // 128 KB
  unsigned*       EA   = (unsigned*)(hl + KH * N_NODES);           // 64 KB
  unsigned*       EB   = EA + KH * 2048;                           // 64 KB
  float*          bmax = (float*)(EB + KH * 2048);                 // 2 KB
  unsigned long long* mbitsT = (unsigned long long*)(scratch + (5u << 20)); // 2 MB
  // top of use: 7 MB

  dim3 ga(N_NODES / 64, KF / 64);
  xe_gemm<<<ga, 256, 0, stream>>>(x, Ww, Wb, al, ar, xeB, hl, EA, EB, bmax);

  if (use_ws) {
    mask_fused<<<(N_NODES * (size_t)N_NODES) / 1024, 256, 0, stream>>>(
        mask, out_mask, mbitsT);
    gat_attn<<<128 * KH, 256, 0, stream>>>(mbitsT, hl, bmax, EA, EB, xeB, out);
  } else {
    mask_pack<<<(N_NODES * (size_t)N_NODES) / 256, 256, 0, stream>>>(mask, mbitsT);
    gat_attn<<<128 * KH, 256, 0, stream>>>(mbitsT, hl, bmax, EA, EB, xeB, out);
    mask_copy<<<(N_NODES * (size_t)N_NODES) / (4 * 256), 256, 0, stream>>>(mask, out_mask);
  }
}

// Round 17
// 201.849 us; speedup vs baseline: 1.2788x; 1.0091x over previous
//
#include <hip/hip_runtime.h>
#include <hip/hip_bf16.h>

// Problem constants (GAT_18176301597437)
#define N_NODES 4096
#define F_IN    256
#define KH      8
#define KF      512          // KH*FPH
#define NEG_SLOPE 0.2f
#define EBIAS   4.0f

typedef _Float16 half8v __attribute__((ext_vector_type(8)));   // MFMA f16 A/B
typedef _Float16 half2v __attribute__((ext_vector_type(2)));   // packed f16 pair
typedef __attribute__((ext_vector_type(4))) float floatx4;     // MFMA C/D

union H8U4 { half8v v; unsigned u[4]; };

__device__ __forceinline__ unsigned short f2h(float f) {
    _Float16 h = (_Float16)f;
    unsigned short u; __builtin_memcpy(&u, &h, 2);
    return u;
}
__device__ __forceinline__ half2v asH2(unsigned u) {
    half2v h; __builtin_memcpy(&h, &u, 4);
    return h;
}
__device__ __forceinline__ unsigned asU(half2v h) {
    unsigned u; __builtin_memcpy(&u, &h, 4);
    return u;
}
// load 8 consecutive fp32, convert to f16 fragment
__device__ __forceinline__ half8v ld8f(const float* p) {
    const float4 a = *(const float4*)p;
    const float4 b = *(const float4*)(p + 4);
    half8v h;
    h[0] = (_Float16)a.x; h[1] = (_Float16)a.y;
    h[2] = (_Float16)a.z; h[3] = (_Float16)a.w;
    h[4] = (_Float16)b.x; h[5] = (_Float16)b.y;
    h[6] = (_Float16)b.z; h[7] = (_Float16)b.w;
    return h;
}

// ---------- mask_fused v3: int4 loads, float4 stores, shfl-OR bit pack -------
__global__ __launch_bounds__(256) void mask_fused(
    const int* __restrict__ mask, float* __restrict__ outm,
    unsigned long long* __restrict__ bits) {
  const int tid = threadIdx.x;
  const size_t t4 = (size_t)blockIdx.x * 256 + tid;     // int4 index
  const int4 mv = ((const int4*)mask)[t4];
  float4 o;
  o.x = mv.x ? 1.f : 0.f; o.y = mv.y ? 1.f : 0.f;
  o.z = mv.z ? 1.f : 0.f; o.w = mv.w ? 1.f : 0.f;
  ((float4*)outm)[t4] = o;
  const unsigned nib = (mv.x ? 1u : 0u) | (mv.y ? 2u : 0u) |
                       (mv.z ? 4u : 0u) | (mv.w ? 8u : 0u);
  unsigned long long wv = (unsigned long long)nib << (4 * (tid & 15));
  wv |= __shfl_xor(wv, 1);
  wv |= __shfl_xor(wv, 2);
  wv |= __shfl_xor(wv, 4);
  wv |= __shfl_xor(wv, 8);
  if ((tid & 15) == 0) {
    const size_t e0 = t4 << 2;            // first element of this 64-group
    const size_t n = e0 >> 12;
    const size_t c = (e0 & 4095) >> 6;
    bits[c * N_NODES + n] = wv;
  }
}

// ---------- fallback pair (scratch inside out_mask region) ----------
__global__ __launch_bounds__(256) void mask_pack(
    const int* __restrict__ mask, unsigned long long* __restrict__ bits) {
  const size_t idx = (size_t)blockIdx.x * 256 + threadIdx.x;
  const unsigned long long b = __ballot(mask[idx] != 0);
  if ((threadIdx.x & 63) == 0) {
    const size_t w = idx >> 6;
    bits[(w & 63) * (size_t)N_NODES + (w >> 6)] = b;
  }
}
__global__ __launch_bounds__(256) void mask_copy(
    const int* __restrict__ mask, float* __restrict__ outm) {
  const size_t i4 = (size_t)blockIdx.x * 256 + threadIdx.x;
  const int4 mv = ((const int4*)mask)[i4];
  float4 o;
  o.x = mv.x ? 1.f : 0.f; o.y = mv.y ? 1.f : 0.f;
  o.z = mv.z ? 1.f : 0.f; o.w = mv.w ? 1.f : 0.f;
  ((float4*)outm)[i4] = o;
}

// ---------- Kernel A: MFMA xe-GEMM + fused hl/EA/EB/bmax epilogue ------------
// Block = (64-row chunk bx, head k), 256 thr = 4 waves; wave = 16 rows x 64
// cols via 4x 16x16 MFMA C-tiles, K=256 in 8 steps of 32. No LDS, no barriers.
__global__ __launch_bounds__(256) void xe_gemm(
    const float* __restrict__ x,
    const float* __restrict__ Ww,
    const float* __restrict__ Wb,
    const float* __restrict__ al,
    const float* __restrict__ ar,
    unsigned short* __restrict__ xeB,
    float* __restrict__ hl,             // [8][4096]
    unsigned* __restrict__ EA,          // [8][2048]
    unsigned* __restrict__ EB,          // [8][2048]
    float* __restrict__ bmax) {         // [8][256]
  const int tid = threadIdx.x;
  const int w = tid >> 6;               // wave = 16-row group
  const int lane = tid & 63;
  const int col16 = lane & 15;
  const int quad = lane >> 4;
  const int bx = blockIdx.x;            // row chunk 0..63
  const int k  = blockIdx.y;            // head
  const int n0 = bx * 64;

  const int rowA = n0 + w * 16 + col16;
  const float* xp  = x  + (size_t)rowA * F_IN + quad * 8;
  const float* wwp = Ww + (size_t)(k * 64 + col16) * F_IN + quad * 8;

  floatx4 acc[4];
  #pragma unroll
  for (int ft = 0; ft < 4; ++ft) acc[ft] = (floatx4){0.f, 0.f, 0.f, 0.f};

  #pragma unroll
  for (int ks = 0; ks < 8; ++ks) {
    const half8v aF = ld8f(xp + ks * 32);
    #pragma unroll
    for (int ft = 0; ft < 4; ++ft) {
      const half8v bF = ld8f(wwp + (size_t)(ft * 16) * F_IN + ks * 32);
      acc[ft] = __builtin_amdgcn_mfma_f32_16x16x32_f16(aF, bF, acc[ft], 0, 0, 0);
    }
  }

  // ---- epilogue: bias, frag-layout xeB store, hl/hr dots, E pairs, bmax ----
  float pl[4] = {0.f, 0.f, 0.f, 0.f};
  float pr[4] = {0.f, 0.f, 0.f, 0.f};
  // xeB address for this lane: [h(2)][f(16)][qd(4)][j(8)] within (k,ft,bx) tile
  const int xoff = (w >> 1) * 512 + col16 * 32
                 + ((w & 1) * 2 + (quad >> 1)) * 8 + (quad & 1) * 4;
  #pragma unroll
  for (int ft = 0; ft < 4; ++ft) {
    const int c = k * 64 + ft * 16 + col16;
    const float wbv = Wb[c];
    const float a_l = al[c];
    const float a_r = ar[c];
    float v[4];
    ushort4 pk;
    #pragma unroll
    for (int i = 0; i < 4; ++i) {
      v[i] = acc[ft][i] + wbv;
      pl[i] = fmaf(v[i], a_l, pl[i]);
      pr[i] = fmaf(v[i], a_r, pr[i]);
    }
    pk.x = f2h(v[0]); pk.y = f2h(v[1]); pk.z = f2h(v[2]); pk.w = f2h(v[3]);
    unsigned short* tile = xeB + ((((size_t)(k * 4 + ft)) * 64 + bx) << 10);
    *(ushort4*)(tile + xoff) = pk;
  }
  // reduce hl/hr over the 16 col16 lanes (butterfly -> all lanes hold sums)
  #pragma unroll
  for (int o = 8; o > 0; o >>= 1) {
    #pragma unroll
    for (int i = 0; i < 4; ++i) {
      pl[i] += __shfl_xor(pl[i], o);
      pr[i] += __shfl_xor(pr[i], o);
    }
  }
  if (col16 == 0) {
    const int n = n0 + w * 16 + quad * 4;   // 4 consecutive rows
    float4 o0 = {pl[0], pl[1], pl[2], pl[3]};
    *(float4*)(hl + k * N_NODES + n) = o0;
    unsigned short e1[4], e2[4];
    #pragma unroll
    for (int i = 0; i < 4; ++i) {
      e1[i] = f2h(__expf(pr[i] - EBIAS));
      e2[i] = f2h(__expf(NEG_SLOPE * (pr[i] - EBIAS)));
    }
    uint2 wa, wbv2;
    wa.x   = (unsigned)e1[0] | ((unsigned)e1[1] << 16);
    wa.y   = (unsigned)e1[2] | ((unsigned)e1[3] << 16);
    wbv2.x = (unsigned)e2[0] | ((unsigned)e2[1] << 16);
    wbv2.y = (unsigned)e2[2] | ((unsigned)e2[3] << 16);
    *(uint2*)(EA + k * 2048 + (n >> 1)) = wa;
    *(uint2*)(EB + k * 2048 + (n >> 1)) = wbv2;
  }
  // per-16-row hr max
  float bm = (col16 == 0)
      ? fmaxf(fmaxf(pr[0], pr[1]), fmaxf(pr[2], pr[3])) : -1e30f;
  bm = fmaxf(bm, __shfl_xor(bm, 16));
  bm = fmaxf(bm, __shfl_xor(bm, 32));
  if (lane == 0) bmax[k * 256 + bx * 4 + w] = bm;
}

// ---------- Kernel D: fused attention, 32 rows/block, XCD-pinned heads -------
__global__ __launch_bounds__(256, 2) void gat_attn(
    const unsigned long long* __restrict__ mbitsT,   // [64 c][4096 n]
    const float* __restrict__ hl,
    const float* __restrict__ bmax,                  // [8][256]
    const unsigned* __restrict__ EA,                 // [8][2048] f16 pairs
    const unsigned* __restrict__ EB,
    const unsigned short* __restrict__ xeB,          // f16 frag tiles
    float* __restrict__ out) {
  __shared__ float lds_acc[4][64][20];   // 20 KB (reused for both phases)
  const int t = threadIdx.x;
  const int w4 = t >> 6;                // wave 0..3 = m-quarter
  const int lane = t & 63;
  const int k  = blockIdx.x & 7;        // XCD-pinned head
  const int rg = blockIdx.x >> 3;
  const int n0 = rg * 32;
  const int row = lane & 15;
  const int quad = lane >> 4;
  const int q8 = quad * 8;

  const float4 bm4 = ((const float4*)bmax)[k * 64 + lane];
  float hm = fmaxf(fmaxf(bm4.x, bm4.y), fmaxf(bm4.z, bm4.w));
  #pragma unroll
  for (int o = 1; o < 64; o <<= 1) hm = fmaxf(hm, __shfl_xor(hm, o));

  const float* hlp = hl + k * N_NODES + n0 + row;
  const float hlA = hlp[0];
  const float hlB = hlp[16];
  const float sA = hlA + hm;
  const float MA = fmaxf(sA, NEG_SLOPE * sA);
  const float sB = hlB + hm;
  const float MB = fmaxf(sB, NEG_SLOPE * sB);
  const float c1Af = __expf(hlA + EBIAS - MA);
  const float c2Af = __expf(NEG_SLOPE * (hlA + EBIAS) - MA);
  const float c1Bf = __expf(hlB + EBIAS - MB);
  const float c2Bf = __expf(NEG_SLOPE * (hlB + EBIAS) - MB);
  const half2v c1A = {(_Float16)c1Af, (_Float16)c1Af};
  const half2v c2A = {(_Float16)c2Af, (_Float16)c2Af};
  const half2v c1B = {(_Float16)c1Bf, (_Float16)c1Bf};
  const half2v c2B = {(_Float16)c2Bf, (_Float16)c2Bf};

  const int c0 = w4 * 16;
  const int cEnd = c0 + 16;

  // running pointers
  const unsigned* pEA = EA + k * 2048 + c0 * 32 + quad * 4;
  const unsigned* pEB = EB + k * 2048 + c0 * 32 + quad * 4;
  const unsigned long long* pM = mbitsT + (size_t)c0 * N_NODES + n0 + row;
  const unsigned short* pB = xeB + (((size_t)k * 4) << 16)
                           + ((size_t)c0 << 10) + row * 32 + q8;

  half8v ones;
  #pragma unroll
  for (int i = 0; i < 8; ++i) ones[i] = (_Float16)1.0f;

  floatx4 accA[4], accB[4];
  #pragma unroll
  for (int ft = 0; ft < 4; ++ft) {
    accA[ft] = (floatx4){0.f, 0.f, 0.f, 0.f};
    accB[ft] = (floatx4){0.f, 0.f, 0.f, 0.f};
  }
  floatx4 dpA = (floatx4){0.f, 0.f, 0.f, 0.f};
  floatx4 dpB = (floatx4){0.f, 0.f, 0.f, 0.f};

  // prefetch chunk c0: EA lo/hi, EB lo/hi, both mask words
  uint4 pA0 = *(const uint4*)pEA;
  uint4 pA1 = *(const uint4*)(pEA + 16);
  uint4 pB0 = *(const uint4*)pEB;
  uint4 pB1 = *(const uint4*)(pEB + 16);
  unsigned long long pMvA = pM[0];
  unsigned long long pMvB = pM[16];

  for (int cc = c0; cc < cEnd; ++cc) {
    // ---- issue shared B loads for this chunk ----
    half8v b0, b1, b2, b3, b4, b5, b6, b7;
    b0 = *(const half8v*)pB;                     b1 = *(const half8v*)(pB + 512);
    b2 = *(const half8v*)(pB + (64 << 10));      b3 = *(const half8v*)(pB + (64 << 10) + 512);
    b4 = *(const half8v*)(pB + (128 << 10));     b5 = *(const half8v*)(pB + (128 << 10) + 512);
    b6 = *(const half8v*)(pB + (192 << 10));     b7 = *(const half8v*)(pB + (192 << 10) + 512);
    pB += 1024;
    // ---- stash current E/mask, prefetch next ----
    const uint4 eA0 = pA0, eA1 = pA1, eB0 = pB0, eB1 = pB1;
    const unsigned long long mbA = pMvA, mbB = pMvB;
    pEA += 32; pEB += 32; pM += N_NODES;
    if (cc + 1 < cEnd) {
      pA0 = *(const uint4*)pEA;
      pA1 = *(const uint4*)(pEA + 16);
      pB0 = *(const uint4*)pEB;
      pB1 = *(const uint4*)(pEB + 16);
      pMvA = pM[0];
      pMvB = pM[16];
    }
    const unsigned ea_lo[4] = {eA0.x, eA0.y, eA0.z, eA0.w};
    const unsigned eb_lo[4] = {eB0.x, eB0.y, eB0.z, eB0.w};
    const unsigned ea_hi[4] = {eA1.x, eA1.y, eA1.z, eA1.w};
    const unsigned eb_hi[4] = {eB1.x, eB1.y, eB1.z, eB1.w};
    // ---- tile A: w-compute + MFMAs ----
    {
      const unsigned mlo = (unsigned)(mbA >> q8);
      const unsigned mhi = (unsigned)(mbA >> (32 + q8));
      H8U4 a0, a1;
      #pragma unroll
      for (int p = 0; p < 4; ++p) {
        const half2v w2 = __builtin_elementwise_max(c1A * asH2(ea_lo[p]),
                                                    c2A * asH2(eb_lo[p]));
        const unsigned tb = mlo >> (2 * p);
        a0.u[p] = asU(w2) & (((tb & 1u) | ((tb & 2u) << 15)) * 0xFFFFu);
      }
      #pragma unroll
      for (int p = 0; p < 4; ++p) {
        const half2v w2 = __builtin_elementwise_max(c1A * asH2(ea_hi[p]),
                                                    c2A * asH2(eb_hi[p]));
        const unsigned tb = mhi >> (2 * p);
        a1.u[p] = asU(w2) & (((tb & 1u) | ((tb & 2u) << 15)) * 0xFFFFu);
      }
      dpA = __builtin_amdgcn_mfma_f32_16x16x32_f16(a0.v, ones, dpA, 0, 0, 0);
      dpA = __builtin_amdgcn_mfma_f32_16x16x32_f16(a1.v, ones, dpA, 0, 0, 0);
      accA[0] = __builtin_amdgcn_mfma_f32_16x16x32_f16(a0.v, b0, accA[0], 0, 0, 0);
      accA[0] = __builtin_amdgcn_mfma_f32_16x16x32_f16(a1.v, b1, accA[0], 0, 0, 0);
      accA[1] = __builtin_amdgcn_mfma_f32_16x16x32_f16(a0.v, b2, accA[1], 0, 0, 0);
      accA[1] = __builtin_amdgcn_mfma_f32_16x16x32_f16(a1.v, b3, accA[1], 0, 0, 0);
      accA[2] = __builtin_amdgcn_mfma_f32_16x16x32_f16(a0.v, b4, accA[2], 0, 0, 0);
      accA[2] = __builtin_amdgcn_mfma_f32_16x16x32_f16(a1.v, b5, accA[2], 0, 0, 0);
      accA[3] = __builtin_amdgcn_mfma_f32_16x16x32_f16(a0.v, b6, accA[3], 0, 0, 0);
      accA[3] = __builtin_amdgcn_mfma_f32_16x16x32_f16(a1.v, b7, accA[3], 0, 0, 0);
    }
    // ---- tile B: w-compute + MFMAs (reuses E regs + B frags) ----
    {
      const unsigned mlo = (unsigned)(mbB >> q8);
      const unsigned mhi = (unsigned)(mbB >> (32 + q8));
      H8U4 a0, a1;
      #pragma unroll
      for (int p = 0; p < 4; ++p) {
        const half2v w2 = __builtin_elementwise_max(c1B * asH2(ea_lo[p]),
                                                    c2B * asH2(eb_lo[p]));
        const unsigned tb = mlo >> (2 * p);
        a0.u[p] = asU(w2) & (((tb & 1u) | ((tb & 2u) << 15)) * 0xFFFFu);
      }
      #pragma unroll
      for (int p = 0; p < 4; ++p) {
        const half2v w2 = __builtin_elementwise_max(c1B * asH2(ea_hi[p]),
                                                    c2B * asH2(eb_hi[p]));
        const unsigned tb = mhi >> (2 * p);
        a1.u[p] = asU(w2) & (((tb & 1u) | ((tb & 2u) << 15)) * 0xFFFFu);
      }
      dpB = __builtin_amdgcn_mfma_f32_16x16x32_f16(a0.v, ones, dpB, 0, 0, 0);
      dpB = __builtin_amdgcn_mfma_f32_16x16x32_f16(a1.v, ones, dpB, 0, 0, 0);
      accB[0] = __builtin_amdgcn_mfma_f32_16x16x32_f16(a0.v, b0, accB[0], 0, 0, 0);
      accB[0] = __builtin_amdgcn_mfma_f32_16x16x32_f16(a1.v, b1, accB[0], 0, 0, 0);
      accB[1] = __builtin_amdgcn_mfma_f32_16x16x32_f16(a0.v, b2, accB[1], 0, 0, 0);
      accB[1] = __builtin_amdgcn_mfma_f32_16x16x32_f16(a1.v, b3, accB[1], 0, 0, 0);
      accB[2] = __builtin_amdgcn_mfma_f32_16x16x32_f16(a0.v, b4, accB[2], 0, 0, 0);
      accB[2] = __builtin_amdgcn_mfma_f32_16x16x32_f16(a1.v, b5, accB[2], 0, 0, 0);
      accB[3] = __builtin_amdgcn_mfma_f32_16x16x32_f16(a0.v, b6, accB[3], 0, 0, 0);
      accB[3] = __builtin_amdgcn_mfma_f32_16x16x32_f16(a1.v, b7, accB[3], 0, 0, 0);
    }
  }

  // ---- phase A epilogue (rows n0..n0+15) ----
  #pragma unroll
  for (int i = 0; i < 16; ++i) lds_acc[w4][lane][i] = accA[i >> 2][i & 3];
  #pragma unroll
  for (int i = 0; i < 4; ++i) lds_acc[w4][lane][16 + i] = dpA[i];
  __syncthreads();
  #pragma unroll
  for (int j = 0; j < 4; ++j) {
    const int sl = 4 * w4 + j;
    float fa = 0.f, dpt = 0.f;
    #pragma unroll
    for (int w2 = 0; w2 < 4; ++w2) {
      fa  += lds_acc[w2][lane][sl];
      dpt += lds_acc[w2][lane][16 + j];
    }
    float v = fa / dpt;
    v = (v > 0.f) ? v : (__expf(v) - 1.f);
    v = (v > 0.f) ? v : (__expf(v) - 1.f);
    out[(size_t)(n0 + quad * 4 + j) * KF + k * 64 + w4 * 16 + row] = v;
  }
  __syncthreads();
  // ---- phase B epilogue (rows n0+16..n0+31) ----
  #pragma unroll
  for (int i = 0; i < 16; ++i) lds_acc[w4][lane][i] = accB[i >> 2][i & 3];
  #pragma unroll
  for (int i = 0; i < 4; ++i) lds_acc[w4][lane][16 + i] = dpB[i];
  __syncthreads();
  #pragma unroll
  for (int j = 0; j < 4; ++j) {
    const int sl = 4 * w4 + j;
    float fa = 0.f, dpt = 0.f;
    #pragma unroll
    for (int w2 = 0; w2 < 4; ++w2) {
      fa  += lds_acc[w2][lane][sl];
      dpt += lds_acc[w2][lane][16 + j];
    }
    float v = fa / dpt;
    v = (v > 0.f) ? v : (__expf(v) - 1.f);
    v = (v > 0.f) ? v : (__expf(v) - 1.f);
    out[(size_t)(n0 + 16 + quad * 4 + j) * KF + k * 64 + w4 * 16 + row] = v;
  }
}

// ---------- launcher ----------
extern "C" void kernel_launch(void* const* d_in, const int* in_sizes, int n_in,
                              void* d_out, int out_size, void* d_ws, size_t ws_size,
                              hipStream_t stream) {
  const float* x    = (const float*)d_in[0];   // (4096,256) fp32
  const float* Ww   = (const float*)d_in[1];   // (512,256)  fp32
  const float* Wb   = (const float*)d_in[2];   // (512,)     fp32
  const float* al   = (const float*)d_in[3];   // (1,8,64)   fp32
  const float* ar   = (const float*)d_in[4];   // (1,8,64)   fp32
  const int*   mask = (const int*)d_in[5];     // (1,4096,4096) int32

  float* out      = (float*)d_out;                    // (4096,512) fp32, 8 MB
  float* out_mask = out + (size_t)N_NODES * KF;       // (1,4096,4096) fp32, 64 MB

  const bool use_ws = (ws_size >= (8u << 20));
  char* scratch = use_ws ? (char*)d_ws : (char*)out_mask;
  unsigned short* xeB  = (unsigned short*)scratch;                 // 4 MB
  float*          hl   = (float*)(scratch + (4u << 20));           // 128 KB
  unsigned*       EA   = (unsigned*)(hl + KH * N_NODES);           // 64 KB
  unsigned*       EB   = EA + KH * 2048;                           // 64 KB
  float*          bmax = (float*)(EB + KH * 2048);                 // 8 KB
  unsigned long long* mbitsT = (unsigned long long*)(scratch + (5u << 20)); // 2 MB
  // top of use: 7 MB

  dim3 ga(N_NODES / 64, KH);
  xe_gemm<<<ga, 256, 0, stream>>>(x, Ww, Wb, al, ar, xeB, hl, EA, EB, bmax);

  if (use_ws) {
    mask_fused<<<(N_NODES * (size_t)N_NODES) / 1024, 256, 0, stream>>>(
        mask, out_mask, mbitsT);
    gat_attn<<<128 * KH, 256, 0, stream>>>(mbitsT, hl, bmax, EA, EB, xeB, out);
  } else {
    mask_pack<<<(N_NODES * (size_t)N_NODES) / 256, 256, 0, stream>>>(mask, mbitsT);
    gat_attn<<<128 * KH, 256, 0, stream>>>(mbitsT, hl, bmax, EA, EB, xeB, out);
    mask_copy<<<(N_NODES * (size_t)N_NODES) / (4 * 256), 256, 0, stream>>>(mask, out_mask);
  }
}

// Round 18
// 199.059 us; speedup vs baseline: 1.2968x; 1.0140x over previous
//
#include <hip/hip_runtime.h>
#include <hip/hip_bf16.h>

// Problem constants (GAT_18176301597437)
#define N_NODES 4096
#define F_IN    256
#define KH      8
#define KF      512          // KH*FPH
#define NEG_SLOPE 0.2f
#define EBIAS   4.0f

typedef _Float16 half8v __attribute__((ext_vector_type(8)));   // MFMA f16 A/B
typedef _Float16 half2v __attribute__((ext_vector_type(2)));   // packed f16 pair
typedef __attribute__((ext_vector_type(4))) float floatx4;     // MFMA C/D

union H8U4 { half8v v; unsigned u[4]; };

__device__ __forceinline__ unsigned short f2h(float f) {
    _Float16 h = (_Float16)f;
    unsigned short u; __builtin_memcpy(&u, &h, 2);
    return u;
}
__device__ __forceinline__ half2v asH2(unsigned u) {
    half2v h; __builtin_memcpy(&h, &u, 4);
    return h;
}
__device__ __forceinline__ unsigned asU(half2v h) {
    unsigned u; __builtin_memcpy(&u, &h, 4);
    return u;
}
// load 8 consecutive fp32, convert to f16 fragment
__device__ __forceinline__ half8v ld8f(const float* p) {
    const float4 a = *(const float4*)p;
    const float4 b = *(const float4*)(p + 4);
    half8v h;
    h[0] = (_Float16)a.x; h[1] = (_Float16)a.y;
    h[2] = (_Float16)a.z; h[3] = (_Float16)a.w;
    h[4] = (_Float16)b.x; h[5] = (_Float16)b.y;
    h[6] = (_Float16)b.z; h[7] = (_Float16)b.w;
    return h;
}

// ---------- device body: mask passthrough + transposed bit-pack --------------
__device__ __forceinline__ void mask_body(
    size_t bid, int tid,
    const int* __restrict__ mask, float* __restrict__ outm,
    unsigned long long* __restrict__ bits) {
  const size_t t4 = bid * 256 + tid;     // int4 index
  const int4 mv = ((const int4*)mask)[t4];
  float4 o;
  o.x = mv.x ? 1.f : 0.f; o.y = mv.y ? 1.f : 0.f;
  o.z = mv.z ? 1.f : 0.f; o.w = mv.w ? 1.f : 0.f;
  ((float4*)outm)[t4] = o;
  const unsigned nib = (mv.x ? 1u : 0u) | (mv.y ? 2u : 0u) |
                       (mv.z ? 4u : 0u) | (mv.w ? 8u : 0u);
  unsigned long long wv = (unsigned long long)nib << (4 * (tid & 15));
  wv |= __shfl_xor(wv, 1);
  wv |= __shfl_xor(wv, 2);
  wv |= __shfl_xor(wv, 4);
  wv |= __shfl_xor(wv, 8);
  if ((tid & 15) == 0) {
    const size_t e0 = t4 << 2;            // first element of this 64-group
    const size_t n = e0 >> 12;
    const size_t c = (e0 & 4095) >> 6;
    bits[c * N_NODES + n] = wv;
  }
}

// ---------- device body: MFMA xe-GEMM + fused hl/EA/EB/bmax epilogue ---------
__device__ __forceinline__ void xe_body(
    int bx, int k, int tid,
    const float* __restrict__ x,
    const float* __restrict__ Ww,
    const float* __restrict__ Wb,
    const float* __restrict__ al,
    const float* __restrict__ ar,
    unsigned short* __restrict__ xeB,
    float* __restrict__ hl,             // [8][4096]
    unsigned* __restrict__ EA,          // [8][2048]
    unsigned* __restrict__ EB,          // [8][2048]
    float* __restrict__ bmax) {         // [8][256]
  const int w = tid >> 6;               // wave = 16-row group
  const int lane = tid & 63;
  const int col16 = lane & 15;
  const int quad = lane >> 4;
  const int n0 = bx * 64;

  const int rowA = n0 + w * 16 + col16;
  const float* xp  = x  + (size_t)rowA * F_IN + quad * 8;
  const float* wwp = Ww + (size_t)(k * 64 + col16) * F_IN + quad * 8;

  floatx4 acc[4];
  #pragma unroll
  for (int ft = 0; ft < 4; ++ft) acc[ft] = (floatx4){0.f, 0.f, 0.f, 0.f};

  #pragma unroll
  for (int ks = 0; ks < 8; ++ks) {
    const half8v aF = ld8f(xp + ks * 32);
    #pragma unroll
    for (int ft = 0; ft < 4; ++ft) {
      const half8v bF = ld8f(wwp + (size_t)(ft * 16) * F_IN + ks * 32);
      acc[ft] = __builtin_amdgcn_mfma_f32_16x16x32_f16(aF, bF, acc[ft], 0, 0, 0);
    }
  }

  float pl[4] = {0.f, 0.f, 0.f, 0.f};
  float pr[4] = {0.f, 0.f, 0.f, 0.f};
  const int xoff = (w >> 1) * 512 + col16 * 32
                 + ((w & 1) * 2 + (quad >> 1)) * 8 + (quad & 1) * 4;
  #pragma unroll
  for (int ft = 0; ft < 4; ++ft) {
    const int c = k * 64 + ft * 16 + col16;
    const float wbv = Wb[c];
    const float a_l = al[c];
    const float a_r = ar[c];
    float v[4];
    ushort4 pk;
    #pragma unroll
    for (int i = 0; i < 4; ++i) {
      v[i] = acc[ft][i] + wbv;
      pl[i] = fmaf(v[i], a_l, pl[i]);
      pr[i] = fmaf(v[i], a_r, pr[i]);
    }
    pk.x = f2h(v[0]); pk.y = f2h(v[1]); pk.z = f2h(v[2]); pk.w = f2h(v[3]);
    unsigned short* tile = xeB + ((((size_t)(k * 4 + ft)) * 64 + bx) << 10);
    *(ushort4*)(tile + xoff) = pk;
  }
  #pragma unroll
  for (int o = 8; o > 0; o >>= 1) {
    #pragma unroll
    for (int i = 0; i < 4; ++i) {
      pl[i] += __shfl_xor(pl[i], o);
      pr[i] += __shfl_xor(pr[i], o);
    }
  }
  if (col16 == 0) {
    const int n = n0 + w * 16 + quad * 4;   // 4 consecutive rows
    float4 o0 = {pl[0], pl[1], pl[2], pl[3]};
    *(float4*)(hl + k * N_NODES + n) = o0;
    unsigned short e1[4], e2[4];
    #pragma unroll
    for (int i = 0; i < 4; ++i) {
      e1[i] = f2h(__expf(pr[i] - EBIAS));
      e2[i] = f2h(__expf(NEG_SLOPE * (pr[i] - EBIAS)));
    }
    uint2 wa, wbv2;
    wa.x   = (unsigned)e1[0] | ((unsigned)e1[1] << 16);
    wa.y   = (unsigned)e1[2] | ((unsigned)e1[3] << 16);
    wbv2.x = (unsigned)e2[0] | ((unsigned)e2[1] << 16);
    wbv2.y = (unsigned)e2[2] | ((unsigned)e2[3] << 16);
    *(uint2*)(EA + k * 2048 + (n >> 1)) = wa;
    *(uint2*)(EB + k * 2048 + (n >> 1)) = wbv2;
  }
  float bm = (col16 == 0)
      ? fmaxf(fmaxf(pr[0], pr[1]), fmaxf(pr[2], pr[3])) : -1e30f;
  bm = fmaxf(bm, __shfl_xor(bm, 16));
  bm = fmaxf(bm, __shfl_xor(bm, 32));
  if (lane == 0) bmax[k * 256 + bx * 4 + w] = bm;
}

// ---------- preamble: xe blocks first (compute) + mask stream (HBM) ----------
__global__ __launch_bounds__(256) void preamble(
    const int* __restrict__ mask, float* __restrict__ outm,
    unsigned long long* __restrict__ bits,
    const float* __restrict__ x, const float* __restrict__ Ww,
    const float* __restrict__ Wb, const float* __restrict__ al,
    const float* __restrict__ ar, unsigned short* __restrict__ xeB,
    float* __restrict__ hl, unsigned* __restrict__ EA,
    unsigned* __restrict__ EB, float* __restrict__ bmax) {
  if (blockIdx.x < 512) {
    xe_body((int)(blockIdx.x & 63), (int)(blockIdx.x >> 6), threadIdx.x,
            x, Ww, Wb, al, ar, xeB, hl, EA, EB, bmax);
  } else {
    mask_body((size_t)blockIdx.x - 512, threadIdx.x, mask, outm, bits);
  }
}

// ---------- fallback kernels (scratch inside out_mask region) ----------
__global__ __launch_bounds__(256) void xe_gemm_k(
    const float* __restrict__ x, const float* __restrict__ Ww,
    const float* __restrict__ Wb, const float* __restrict__ al,
    const float* __restrict__ ar, unsigned short* __restrict__ xeB,
    float* __restrict__ hl, unsigned* __restrict__ EA,
    unsigned* __restrict__ EB, float* __restrict__ bmax) {
  xe_body(blockIdx.x, blockIdx.y, threadIdx.x,
          x, Ww, Wb, al, ar, xeB, hl, EA, EB, bmax);
}
__global__ __launch_bounds__(256) void mask_pack(
    const int* __restrict__ mask, unsigned long long* __restrict__ bits) {
  const size_t idx = (size_t)blockIdx.x * 256 + threadIdx.x;
  const unsigned long long b = __ballot(mask[idx] != 0);
  if ((threadIdx.x & 63) == 0) {
    const size_t w = idx >> 6;
    bits[(w & 63) * (size_t)N_NODES + (w >> 6)] = b;
  }
}
__global__ __launch_bounds__(256) void mask_copy(
    const int* __restrict__ mask, float* __restrict__ outm) {
  const size_t i4 = (size_t)blockIdx.x * 256 + threadIdx.x;
  const int4 mv = ((const int4*)mask)[i4];
  float4 o;
  o.x = mv.x ? 1.f : 0.f; o.y = mv.y ? 1.f : 0.f;
  o.z = mv.z ? 1.f : 0.f; o.w = mv.w ? 1.f : 0.f;
  ((float4*)outm)[i4] = o;
}

// ---------- Kernel D: fused attention, 32 rows/block, full 1-deep pipeline ---
// Block = 256 thr = 4 waves = (32-row group, head); wave = 16 m-chunks.
// B, E, and mask are ALL prefetched one chunk ahead -> every load has a full
// chunk (~500 cyc) of latency cover instead of ~120.
__global__ __launch_bounds__(256, 2) void gat_attn(
    const unsigned long long* __restrict__ mbitsT,   // [64 c][4096 n]
    const float* __restrict__ hl,
    const float* __restrict__ bmax,                  // [8][256]
    const unsigned* __restrict__ EA,                 // [8][2048] f16 pairs
    const unsigned* __restrict__ EB,
    const unsigned short* __restrict__ xeB,          // f16 frag tiles
    float* __restrict__ out) {
  __shared__ float lds_acc[4][64][20];   // 20 KB (reused for both phases)
  const int t = threadIdx.x;
  const int w4 = t >> 6;                // wave 0..3 = m-quarter
  const int lane = t & 63;
  const int k  = blockIdx.x & 7;        // XCD-pinned head
  const int rg = blockIdx.x >> 3;
  const int n0 = rg * 32;
  const int row = lane & 15;
  const int quad = lane >> 4;
  const int q8 = quad * 8;

  const float4 bm4 = ((const float4*)bmax)[k * 64 + lane];
  float hm = fmaxf(fmaxf(bm4.x, bm4.y), fmaxf(bm4.z, bm4.w));
  #pragma unroll
  for (int o = 1; o < 64; o <<= 1) hm = fmaxf(hm, __shfl_xor(hm, o));

  const float* hlp = hl + k * N_NODES + n0 + row;
  const float hlA = hlp[0];
  const float hlB = hlp[16];
  const float sA = hlA + hm;
  const float MA = fmaxf(sA, NEG_SLOPE * sA);
  const float sB = hlB + hm;
  const float MB = fmaxf(sB, NEG_SLOPE * sB);
  const float c1Af = __expf(hlA + EBIAS - MA);
  const float c2Af = __expf(NEG_SLOPE * (hlA + EBIAS) - MA);
  const float c1Bf = __expf(hlB + EBIAS - MB);
  const float c2Bf = __expf(NEG_SLOPE * (hlB + EBIAS) - MB);
  const half2v c1A = {(_Float16)c1Af, (_Float16)c1Af};
  const half2v c2A = {(_Float16)c2Af, (_Float16)c2Af};
  const half2v c1B = {(_Float16)c1Bf, (_Float16)c1Bf};
  const half2v c2B = {(_Float16)c2Bf, (_Float16)c2Bf};

  const int c0 = w4 * 16;
  const int cEnd = c0 + 16;

  // running pointers
  const unsigned* pEA = EA + k * 2048 + c0 * 32 + quad * 4;
  const unsigned* pEB = EB + k * 2048 + c0 * 32 + quad * 4;
  const unsigned long long* pM = mbitsT + (size_t)c0 * N_NODES + n0 + row;
  const unsigned short* pB = xeB + (((size_t)k * 4) << 16)
                           + ((size_t)c0 << 10) + row * 32 + q8;

  half8v ones;
  #pragma unroll
  for (int i = 0; i < 8; ++i) ones[i] = (_Float16)1.0f;

  floatx4 accA[4], accB[4];
  #pragma unroll
  for (int ft = 0; ft < 4; ++ft) {
    accA[ft] = (floatx4){0.f, 0.f, 0.f, 0.f};
    accB[ft] = (floatx4){0.f, 0.f, 0.f, 0.f};
  }
  floatx4 dpA = (floatx4){0.f, 0.f, 0.f, 0.f};
  floatx4 dpB = (floatx4){0.f, 0.f, 0.f, 0.f};

  // prefetch chunk c0: B frags, EA lo/hi, EB lo/hi, both mask words
  half8v nb0, nb1, nb2, nb3, nb4, nb5, nb6, nb7;
  nb0 = *(const half8v*)pB;                     nb1 = *(const half8v*)(pB + 512);
  nb2 = *(const half8v*)(pB + (64 << 10));      nb3 = *(const half8v*)(pB + (64 << 10) + 512);
  nb4 = *(const half8v*)(pB + (128 << 10));     nb5 = *(const half8v*)(pB + (128 << 10) + 512);
  nb6 = *(const half8v*)(pB + (192 << 10));     nb7 = *(const half8v*)(pB + (192 << 10) + 512);
  pB += 1024;
  uint4 pA0 = *(const uint4*)pEA;
  uint4 pA1 = *(const uint4*)(pEA + 16);
  uint4 pB0 = *(const uint4*)pEB;
  uint4 pB1 = *(const uint4*)(pEB + 16);
  unsigned long long pMvA = pM[0];
  unsigned long long pMvB = pM[16];

  for (int cc = c0; cc < cEnd; ++cc) {
    // ---- consume prefetched B; prefetch next chunk's B ----
    const half8v b0 = nb0, b1 = nb1, b2 = nb2, b3 = nb3;
    const half8v b4 = nb4, b5 = nb5, b6 = nb6, b7 = nb7;
    const uint4 eA0 = pA0, eA1 = pA1, eB0 = pB0, eB1 = pB1;
    const unsigned long long mbA = pMvA, mbB = pMvB;
    pEA += 32; pEB += 32; pM += N_NODES;
    if (cc + 1 < cEnd) {
      nb0 = *(const half8v*)pB;                     nb1 = *(const half8v*)(pB + 512);
      nb2 = *(const half8v*)(pB + (64 << 10));      nb3 = *(const half8v*)(pB + (64 << 10) + 512);
      nb4 = *(const half8v*)(pB + (128 << 10));     nb5 = *(const half8v*)(pB + (128 << 10) + 512);
      nb6 = *(const half8v*)(pB + (192 << 10));     nb7 = *(const half8v*)(pB + (192 << 10) + 512);
      pB += 1024;
      pA0 = *(const uint4*)pEA;
      pA1 = *(const uint4*)(pEA + 16);
      pB0 = *(const uint4*)pEB;
      pB1 = *(const uint4*)(pEB + 16);
      pMvA = pM[0];
      pMvB = pM[16];
    }
    const unsigned ea_lo[4] = {eA0.x, eA0.y, eA0.z, eA0.w};
    const unsigned eb_lo[4] = {eB0.x, eB0.y, eB0.z, eB0.w};
    const unsigned ea_hi[4] = {eA1.x, eA1.y, eA1.z, eA1.w};
    const unsigned eb_hi[4] = {eB1.x, eB1.y, eB1.z, eB1.w};
    // ---- tile A: w-compute + MFMAs ----
    {
      const unsigned mlo = (unsigned)(mbA >> q8);
      const unsigned mhi = (unsigned)(mbA >> (32 + q8));
      H8U4 a0, a1;
      #pragma unroll
      for (int p = 0; p < 4; ++p) {
        const half2v w2 = __builtin_elementwise_max(c1A * asH2(ea_lo[p]),
                                                    c2A * asH2(eb_lo[p]));
        const unsigned tb = mlo >> (2 * p);
        a0.u[p] = asU(w2) & (((tb & 1u) | ((tb & 2u) << 15)) * 0xFFFFu);
      }
      #pragma unroll
      for (int p = 0; p < 4; ++p) {
        const half2v w2 = __builtin_elementwise_max(c1A * asH2(ea_hi[p]),
                                                    c2A * asH2(eb_hi[p]));
        const unsigned tb = mhi >> (2 * p);
        a1.u[p] = asU(w2) & (((tb & 1u) | ((tb & 2u) << 15)) * 0xFFFFu);
      }
      dpA = __builtin_amdgcn_mfma_f32_16x16x32_f16(a0.v, ones, dpA, 0, 0, 0);
      dpA = __builtin_amdgcn_mfma_f32_16x16x32_f16(a1.v, ones, dpA, 0, 0, 0);
      accA[0] = __builtin_amdgcn_mfma_f32_16x16x32_f16(a0.v, b0, accA[0], 0, 0, 0);
      accA[0] = __builtin_amdgcn_mfma_f32_16x16x32_f16(a1.v, b1, accA[0], 0, 0, 0);
      accA[1] = __builtin_amdgcn_mfma_f32_16x16x32_f16(a0.v, b2, accA[1], 0, 0, 0);
      accA[1] = __builtin_amdgcn_mfma_f32_16x16x32_f16(a1.v, b3, accA[1], 0, 0, 0);
      accA[2] = __builtin_amdgcn_mfma_f32_16x16x32_f16(a0.v, b4, accA[2], 0, 0, 0);
      accA[2] = __builtin_amdgcn_mfma_f32_16x16x32_f16(a1.v, b5, accA[2], 0, 0, 0);
      accA[3] = __builtin_amdgcn_mfma_f32_16x16x32_f16(a0.v, b6, accA[3], 0, 0, 0);
      accA[3] = __builtin_amdgcn_mfma_f32_16x16x32_f16(a1.v, b7, accA[3], 0, 0, 0);
    }
    // ---- tile B: w-compute + MFMAs (reuses E regs + B frags) ----
    {
      const unsigned mlo = (unsigned)(mbB >> q8);
      const unsigned mhi = (unsigned)(mbB >> (32 + q8));
      H8U4 a0, a1;
      #pragma unroll
      for (int p = 0; p < 4; ++p) {
        const half2v w2 = __builtin_elementwise_max(c1B * asH2(ea_lo[p]),
                                                    c2B * asH2(eb_lo[p]));
        const unsigned tb = mlo >> (2 * p);
        a0.u[p] = asU(w2) & (((tb & 1u) | ((tb & 2u) << 15)) * 0xFFFFu);
      }
      #pragma unroll
      for (int p = 0; p < 4; ++p) {
        const half2v w2 = __builtin_elementwise_max(c1B * asH2(ea_hi[p]),
                                                    c2B * asH2(eb_hi[p]));
        const unsigned tb = mhi >> (2 * p);
        a1.u[p] = asU(w2) & (((tb & 1u) | ((tb & 2u) << 15)) * 0xFFFFu);
      }
      dpB = __builtin_amdgcn_mfma_f32_16x16x32_f16(a0.v, ones, dpB, 0, 0, 0);
      dpB = __builtin_amdgcn_mfma_f32_16x16x32_f16(a1.v, ones, dpB, 0, 0, 0);
      accB[0] = __builtin_amdgcn_mfma_f32_16x16x32_f16(a0.v, b0, accB[0], 0, 0, 0);
      accB[0] = __builtin_amdgcn_mfma_f32_16x16x32_f16(a1.v, b1, accB[0], 0, 0, 0);
      accB[1] = __builtin_amdgcn_mfma_f32_16x16x32_f16(a0.v, b2, accB[1], 0, 0, 0);
      accB[1] = __builtin_amdgcn_mfma_f32_16x16x32_f16(a1.v, b3, accB[1], 0, 0, 0);
      accB[2] = __builtin_amdgcn_mfma_f32_16x16x32_f16(a0.v, b4, accB[2], 0, 0, 0);
      accB[2] = __builtin_amdgcn_mfma_f32_16x16x32_f16(a1.v, b5, accB[2], 0, 0, 0);
      accB[3] = __builtin_amdgcn_mfma_f32_16x16x32_f16(a0.v, b6, accB[3], 0, 0, 0);
      accB[3] = __builtin_amdgcn_mfma_f32_16x16x32_f16(a1.v, b7, accB[3], 0, 0, 0);
    }
  }

  // ---- phase A epilogue (rows n0..n0+15) ----
  #pragma unroll
  for (int i = 0; i < 16; ++i) lds_acc[w4][lane][i] = accA[i >> 2][i & 3];
  #pragma unroll
  for (int i = 0; i < 4; ++i) lds_acc[w4][lane][16 + i] = dpA[i];
  __syncthreads();
  #pragma unroll
  for (int j = 0; j < 4; ++j) {
    const int sl = 4 * w4 + j;
    float fa = 0.f, dpt = 0.f;
    #pragma unroll
    for (int w2 = 0; w2 < 4; ++w2) {
      fa  += lds_acc[w2][lane][sl];
      dpt += lds_acc[w2][lane][16 + j];
    }
    float v = fa / dpt;
    v = (v > 0.f) ? v : (__expf(v) - 1.f);
    v = (v > 0.f) ? v : (__expf(v) - 1.f);
    out[(size_t)(n0 + quad * 4 + j) * KF + k * 64 + w4 * 16 + row] = v;
  }
  __syncthreads();
  // ---- phase B epilogue (rows n0+16..n0+31) ----
  #pragma unroll
  for (int i = 0; i < 16; ++i) lds_acc[w4][lane][i] = accB[i >> 2][i & 3];
  #pragma unroll
  for (int i = 0; i < 4; ++i) lds_acc[w4][lane][16 + i] = dpB[i];
  __syncthreads();
  #pragma unroll
  for (int j = 0; j < 4; ++j) {
    const int sl = 4 * w4 + j;
    float fa = 0.f, dpt = 0.f;
    #pragma unroll
    for (int w2 = 0; w2 < 4; ++w2) {
      fa  += lds_acc[w2][lane][sl];
      dpt += lds_acc[w2][lane][16 + j];
    }
    float v = fa / dpt;
    v = (v > 0.f) ? v : (__expf(v) - 1.f);
    v = (v > 0.f) ? v : (__expf(v) - 1.f);
    out[(size_t)(n0 + 16 + quad * 4 + j) * KF + k * 64 + w4 * 16 + row] = v;
  }
}

// ---------- launcher ----------
extern "C" void kernel_launch(void* const* d_in, const int* in_sizes, int n_in,
                              void* d_out, int out_size, void* d_ws, size_t ws_size,
                              hipStream_t stream) {
  const float* x    = (const float*)d_in[0];   // (4096,256) fp32
  const float* Ww   = (const float*)d_in[1];   // (512,256)  fp32
  const float* Wb   = (const float*)d_in[2];   // (512,)     fp32
  const float* al   = (const float*)d_in[3];   // (1,8,64)   fp32
  const float* ar   = (const float*)d_in[4];   // (1,8,64)   fp32
  const int*   mask = (const int*)d_in[5];     // (1,4096,4096) int32

  float* out      = (float*)d_out;                    // (4096,512) fp32, 8 MB
  float* out_mask = out + (size_t)N_NODES * KF;       // (1,4096,4096) fp32, 64 MB

  const bool use_ws = (ws_size >= (8u << 20));
  char* scratch = use_ws ? (char*)d_ws : (char*)out_mask;
  unsigned short* xeB  = (unsigned short*)scratch;                 // 4 MB
  float*          hl   = (float*)(scratch + (4u << 20));           // 128 KB
  unsigned*       EA   = (unsigned*)(hl + KH * N_NODES);           // 64 KB
  unsigned*       EB   = EA + KH * 2048;                           // 64 KB
  float*          bmax = (float*)(EB + KH * 2048);                 // 8 KB
  unsigned long long* mbitsT = (unsigned long long*)(scratch + (5u << 20)); // 2 MB
  // top of use: 7 MB

  if (use_ws) {
    // fused preamble: 512 xe blocks first (compute), then 65536 mask blocks
    preamble<<<512 + (N_NODES * (size_t)N_NODES) / 1024, 256, 0, stream>>>(
        mask, out_mask, mbitsT, x, Ww, Wb, al, ar, xeB, hl, EA, EB, bmax);
    gat_attn<<<128 * KH, 256, 0, stream>>>(mbitsT, hl, bmax, EA, EB, xeB, out);
  } else {
    dim3 ga(N_NODES / 64, KH);
    xe_gemm_k<<<ga, 256, 0, stream>>>(x, Ww, Wb, al, ar, xeB, hl, EA, EB, bmax);
    mask_pack<<<(N_NODES * (size_t)N_NODES) / 256, 256, 0, stream>>>(mask, mbitsT);
    gat_attn<<<128 * KH, 256, 0, stream>>>(mbitsT, hl, bmax, EA, EB, xeB, out);
    mask_copy<<<(N_NODES * (size_t)N_NODES) / (4 * 256), 256, 0, stream>>>(mask, out_mask);
  }
}

// Round 20
// 198.261 us; speedup vs baseline: 1.3020x; 1.0040x over previous
//
#include <hip/hip_runtime.h>
#include <hip/hip_bf16.h>

// Problem constants (GAT_18176301597437)
#define N_NODES 4096
#define F_IN    256
#define KH      8
#define KF      512          // KH*FPH
#define NEG_SLOPE 0.2f
#define EBIAS   4.0f

typedef _Float16 half8v __attribute__((ext_vector_type(8)));   // MFMA f16 A/B
typedef _Float16 half2v __attribute__((ext_vector_type(2)));   // packed f16 pair
typedef __attribute__((ext_vector_type(4))) float floatx4;     // MFMA C/D (also used for NT stores)

union H8U4 { half8v v; unsigned u[4]; };

__device__ __forceinline__ unsigned short f2h(float f) {
    _Float16 h = (_Float16)f;
    unsigned short u; __builtin_memcpy(&u, &h, 2);
    return u;
}
__device__ __forceinline__ half2v asH2(unsigned u) {
    half2v h; __builtin_memcpy(&h, &u, 4);
    return h;
}
__device__ __forceinline__ unsigned asU(half2v h) {
    unsigned u; __builtin_memcpy(&u, &h, 4);
    return u;
}
// load 8 consecutive fp32, convert to f16 fragment
__device__ __forceinline__ half8v ld8f(const float* p) {
    const float4 a = *(const float4*)p;
    const float4 b = *(const float4*)(p + 4);
    half8v h;
    h[0] = (_Float16)a.x; h[1] = (_Float16)a.y;
    h[2] = (_Float16)a.z; h[3] = (_Float16)a.w;
    h[4] = (_Float16)b.x; h[5] = (_Float16)b.y;
    h[6] = (_Float16)b.z; h[7] = (_Float16)b.w;
    return h;
}

// ---------- device body: mask passthrough + bit-pack, 4 int4 per thread ------
// Batched loads (4 outstanding 16B loads/thread) -> 4 independent shfl-OR
// trees. outm stores are non-temporal (write-only stream) via clang ext-vector.
__device__ __forceinline__ void mask_body4(
    size_t bid, int tid,
    const int* __restrict__ mask, float* __restrict__ outm,
    unsigned long long* __restrict__ bits) {
  const size_t base = bid * 1024 + tid;   // int4 index, chunk stride 256
  int4 mv[4];
  #pragma unroll
  for (int c = 0; c < 4; ++c) mv[c] = ((const int4*)mask)[base + c * 256];
  #pragma unroll
  for (int c = 0; c < 4; ++c) {
    const size_t t4 = base + c * 256;
    floatx4 o;
    o[0] = mv[c].x ? 1.f : 0.f; o[1] = mv[c].y ? 1.f : 0.f;
    o[2] = mv[c].z ? 1.f : 0.f; o[3] = mv[c].w ? 1.f : 0.f;
    __builtin_nontemporal_store(o, (floatx4*)outm + t4);
    const unsigned nib = (mv[c].x ? 1u : 0u) | (mv[c].y ? 2u : 0u) |
                         (mv[c].z ? 4u : 0u) | (mv[c].w ? 8u : 0u);
    unsigned long long wv = (unsigned long long)nib << (4 * (tid & 15));
    wv |= __shfl_xor(wv, 1);
    wv |= __shfl_xor(wv, 2);
    wv |= __shfl_xor(wv, 4);
    wv |= __shfl_xor(wv, 8);
    if ((tid & 15) == 0) {
      const size_t e0 = t4 << 2;            // first element of this 64-group
      const size_t n = e0 >> 12;
      const size_t cc = (e0 & 4095) >> 6;
      bits[cc * N_NODES + n] = wv;
    }
  }
}

// ---------- device body: MFMA xe-GEMM + fused hl/EA/EB/bmax epilogue ---------
__device__ __forceinline__ void xe_body(
    int bx, int k, int tid,
    const float* __restrict__ x,
    const float* __restrict__ Ww,
    const float* __restrict__ Wb,
    const float* __restrict__ al,
    const float* __restrict__ ar,
    unsigned short* __restrict__ xeB,
    float* __restrict__ hl,             // [8][4096]
    unsigned* __restrict__ EA,          // [8][2048]
    unsigned* __restrict__ EB,          // [8][2048]
    float* __restrict__ bmax) {         // [8][256]
  const int w = tid >> 6;               // wave = 16-row group
  const int lane = tid & 63;
  const int col16 = lane & 15;
  const int quad = lane >> 4;
  const int n0 = bx * 64;

  const int rowA = n0 + w * 16 + col16;
  const float* xp  = x  + (size_t)rowA * F_IN + quad * 8;
  const float* wwp = Ww + (size_t)(k * 64 + col16) * F_IN + quad * 8;

  floatx4 acc[4];
  #pragma unroll
  for (int ft = 0; ft < 4; ++ft) acc[ft] = (floatx4){0.f, 0.f, 0.f, 0.f};

  #pragma unroll
  for (int ks = 0; ks < 8; ++ks) {
    const half8v aF = ld8f(xp + ks * 32);
    #pragma unroll
    for (int ft = 0; ft < 4; ++ft) {
      const half8v bF = ld8f(wwp + (size_t)(ft * 16) * F_IN + ks * 32);
      acc[ft] = __builtin_amdgcn_mfma_f32_16x16x32_f16(aF, bF, acc[ft], 0, 0, 0);
    }
  }

  float pl[4] = {0.f, 0.f, 0.f, 0.f};
  float pr[4] = {0.f, 0.f, 0.f, 0.f};
  const int xoff = (w >> 1) * 512 + col16 * 32
                 + ((w & 1) * 2 + (quad >> 1)) * 8 + (quad & 1) * 4;
  #pragma unroll
  for (int ft = 0; ft < 4; ++ft) {
    const int c = k * 64 + ft * 16 + col16;
    const float wbv = Wb[c];
    const float a_l = al[c];
    const float a_r = ar[c];
    float v[4];
    ushort4 pk;
    #pragma unroll
    for (int i = 0; i < 4; ++i) {
      v[i] = acc[ft][i] + wbv;
      pl[i] = fmaf(v[i], a_l, pl[i]);
      pr[i] = fmaf(v[i], a_r, pr[i]);
    }
    pk.x = f2h(v[0]); pk.y = f2h(v[1]); pk.z = f2h(v[2]); pk.w = f2h(v[3]);
    unsigned short* tile = xeB + ((((size_t)(k * 4 + ft)) * 64 + bx) << 10);
    *(ushort4*)(tile + xoff) = pk;
  }
  #pragma unroll
  for (int o = 8; o > 0; o >>= 1) {
    #pragma unroll
    for (int i = 0; i < 4; ++i) {
      pl[i] += __shfl_xor(pl[i], o);
      pr[i] += __shfl_xor(pr[i], o);
    }
  }
  if (col16 == 0) {
    const int n = n0 + w * 16 + quad * 4;   // 4 consecutive rows
    float4 o0 = {pl[0], pl[1], pl[2], pl[3]};
    *(float4*)(hl + k * N_NODES + n) = o0;
    unsigned short e1[4], e2[4];
    #pragma unroll
    for (int i = 0; i < 4; ++i) {
      e1[i] = f2h(__expf(pr[i] - EBIAS));
      e2[i] = f2h(__expf(NEG_SLOPE * (pr[i] - EBIAS)));
    }
    uint2 wa, wbv2;
    wa.x   = (unsigned)e1[0] | ((unsigned)e1[1] << 16);
    wa.y   = (unsigned)e1[2] | ((unsigned)e1[3] << 16);
    wbv2.x = (unsigned)e2[0] | ((unsigned)e2[1] << 16);
    wbv2.y = (unsigned)e2[2] | ((unsigned)e2[3] << 16);
    *(uint2*)(EA + k * 2048 + (n >> 1)) = wa;
    *(uint2*)(EB + k * 2048 + (n >> 1)) = wbv2;
  }
  float bm = (col16 == 0)
      ? fmaxf(fmaxf(pr[0], pr[1]), fmaxf(pr[2], pr[3])) : -1e30f;
  bm = fmaxf(bm, __shfl_xor(bm, 16));
  bm = fmaxf(bm, __shfl_xor(bm, 32));
  if (lane == 0) bmax[k * 256 + bx * 4 + w] = bm;
}

// ---------- preamble: xe blocks first (compute) + mask stream (HBM) ----------
__global__ __launch_bounds__(256) void preamble(
    const int* __restrict__ mask, float* __restrict__ outm,
    unsigned long long* __restrict__ bits,
    const float* __restrict__ x, const float* __restrict__ Ww,
    const float* __restrict__ Wb, const float* __restrict__ al,
    const float* __restrict__ ar, unsigned short* __restrict__ xeB,
    float* __restrict__ hl, unsigned* __restrict__ EA,
    unsigned* __restrict__ EB, float* __restrict__ bmax) {
  if (blockIdx.x < 512) {
    xe_body((int)(blockIdx.x & 63), (int)(blockIdx.x >> 6), threadIdx.x,
            x, Ww, Wb, al, ar, xeB, hl, EA, EB, bmax);
  } else {
    mask_body4((size_t)blockIdx.x - 512, threadIdx.x, mask, outm, bits);
  }
}

// ---------- fallback kernels (scratch inside out_mask region) ----------
__global__ __launch_bounds__(256) void xe_gemm_k(
    const float* __restrict__ x, const float* __restrict__ Ww,
    const float* __restrict__ Wb, const float* __restrict__ al,
    const float* __restrict__ ar, unsigned short* __restrict__ xeB,
    float* __restrict__ hl, unsigned* __restrict__ EA,
    unsigned* __restrict__ EB, float* __restrict__ bmax) {
  xe_body(blockIdx.x, blockIdx.y, threadIdx.x,
          x, Ww, Wb, al, ar, xeB, hl, EA, EB, bmax);
}
__global__ __launch_bounds__(256) void mask_pack(
    const int* __restrict__ mask, unsigned long long* __restrict__ bits) {
  const size_t idx = (size_t)blockIdx.x * 256 + threadIdx.x;
  const unsigned long long b = __ballot(mask[idx] != 0);
  if ((threadIdx.x & 63) == 0) {
    const size_t w = idx >> 6;
    bits[(w & 63) * (size_t)N_NODES + (w >> 6)] = b;
  }
}
__global__ __launch_bounds__(256) void mask_copy(
    const int* __restrict__ mask, float* __restrict__ outm) {
  const size_t i4 = (size_t)blockIdx.x * 256 + threadIdx.x;
  const int4 mv = ((const int4*)mask)[i4];
  float4 o;
  o.x = mv.x ? 1.f : 0.f; o.y = mv.y ? 1.f : 0.f;
  o.z = mv.z ? 1.f : 0.f; o.w = mv.w ? 1.f : 0.f;
  ((float4*)outm)[i4] = o;
}

// ---------- Kernel D: fused attention, 32 rows/block, full 1-deep pipeline ---
__global__ __launch_bounds__(256, 2) void gat_attn(
    const unsigned long long* __restrict__ mbitsT,   // [64 c][4096 n]
    const float* __restrict__ hl,
    const float* __restrict__ bmax,                  // [8][256]
    const unsigned* __restrict__ EA,                 // [8][2048] f16 pairs
    const unsigned* __restrict__ EB,
    const unsigned short* __restrict__ xeB,          // f16 frag tiles
    float* __restrict__ out) {
  __shared__ float lds_acc[4][64][20];   // 20 KB (reused for both phases)
  const int t = threadIdx.x;
  const int w4 = t >> 6;                // wave 0..3 = m-quarter
  const int lane = t & 63;
  const int k  = blockIdx.x & 7;        // XCD-pinned head
  const int rg = blockIdx.x >> 3;
  const int n0 = rg * 32;
  const int row = lane & 15;
  const int quad = lane >> 4;
  const int q8 = quad * 8;

  const float4 bm4 = ((const float4*)bmax)[k * 64 + lane];
  float hm = fmaxf(fmaxf(bm4.x, bm4.y), fmaxf(bm4.z, bm4.w));
  #pragma unroll
  for (int o = 1; o < 64; o <<= 1) hm = fmaxf(hm, __shfl_xor(hm, o));

  const float* hlp = hl + k * N_NODES + n0 + row;
  const float hlA = hlp[0];
  const float hlB = hlp[16];
  const float sA = hlA + hm;
  const float MA = fmaxf(sA, NEG_SLOPE * sA);
  const float sB = hlB + hm;
  const float MB = fmaxf(sB, NEG_SLOPE * sB);
  const float c1Af = __expf(hlA + EBIAS - MA);
  const float c2Af = __expf(NEG_SLOPE * (hlA + EBIAS) - MA);
  const float c1Bf = __expf(hlB + EBIAS - MB);
  const float c2Bf = __expf(NEG_SLOPE * (hlB + EBIAS) - MB);
  const half2v c1A = {(_Float16)c1Af, (_Float16)c1Af};
  const half2v c2A = {(_Float16)c2Af, (_Float16)c2Af};
  const half2v c1B = {(_Float16)c1Bf, (_Float16)c1Bf};
  const half2v c2B = {(_Float16)c2Bf, (_Float16)c2Bf};

  const int c0 = w4 * 16;
  const int cEnd = c0 + 16;

  // running pointers
  const unsigned* pEA = EA + k * 2048 + c0 * 32 + quad * 4;
  const unsigned* pEB = EB + k * 2048 + c0 * 32 + quad * 4;
  const unsigned long long* pM = mbitsT + (size_t)c0 * N_NODES + n0 + row;
  const unsigned short* pB = xeB + (((size_t)k * 4) << 16)
                           + ((size_t)c0 << 10) + row * 32 + q8;

  half8v ones;
  #pragma unroll
  for (int i = 0; i < 8; ++i) ones[i] = (_Float16)1.0f;

  floatx4 accA[4], accB[4];
  #pragma unroll
  for (int ft = 0; ft < 4; ++ft) {
    accA[ft] = (floatx4){0.f, 0.f, 0.f, 0.f};
    accB[ft] = (floatx4){0.f, 0.f, 0.f, 0.f};
  }
  floatx4 dpA = (floatx4){0.f, 0.f, 0.f, 0.f};
  floatx4 dpB = (floatx4){0.f, 0.f, 0.f, 0.f};

  // prefetch chunk c0: B frags, EA lo/hi, EB lo/hi, both mask words
  half8v nb0, nb1, nb2, nb3, nb4, nb5, nb6, nb7;
  nb0 = *(const half8v*)pB;                     nb1 = *(const half8v*)(pB + 512);
  nb2 = *(const half8v*)(pB + (64 << 10));      nb3 = *(const half8v*)(pB + (64 << 10) + 512);
  nb4 = *(const half8v*)(pB + (128 << 10));     nb5 = *(const half8v*)(pB + (128 << 10) + 512);
  nb6 = *(const half8v*)(pB + (192 << 10));     nb7 = *(const half8v*)(pB + (192 << 10) + 512);
  pB += 1024;
  uint4 pA0 = *(const uint4*)pEA;
  uint4 pA1 = *(const uint4*)(pEA + 16);
  uint4 pB0 = *(const uint4*)pEB;
  uint4 pB1 = *(const uint4*)(pEB + 16);
  unsigned long long pMvA = pM[0];
  unsigned long long pMvB = pM[16];

  for (int cc = c0; cc < cEnd; ++cc) {
    // ---- consume prefetched B; prefetch next chunk's B ----
    const half8v b0 = nb0, b1 = nb1, b2 = nb2, b3 = nb3;
    const half8v b4 = nb4, b5 = nb5, b6 = nb6, b7 = nb7;
    const uint4 eA0 = pA0, eA1 = pA1, eB0 = pB0, eB1 = pB1;
    const unsigned long long mbA = pMvA, mbB = pMvB;
    pEA += 32; pEB += 32; pM += N_NODES;
    if (cc + 1 < cEnd) {
      nb0 = *(const half8v*)pB;                     nb1 = *(const half8v*)(pB + 512);
      nb2 = *(const half8v*)(pB + (64 << 10));      nb3 = *(const half8v*)(pB + (64 << 10) + 512);
      nb4 = *(const half8v*)(pB + (128 << 10));     nb5 = *(const half8v*)(pB + (128 << 10) + 512);
      nb6 = *(const half8v*)(pB + (192 << 10));     nb7 = *(const half8v*)(pB + (192 << 10) + 512);
      pB += 1024;
      pA0 = *(const uint4*)pEA;
      pA1 = *(const uint4*)(pEA + 16);
      pB0 = *(const uint4*)pEB;
      pB1 = *(const uint4*)(pEB + 16);
      pMvA = pM[0];
      pMvB = pM[16];
    }
    const unsigned ea_lo[4] = {eA0.x, eA0.y, eA0.z, eA0.w};
    const unsigned eb_lo[4] = {eB0.x, eB0.y, eB0.z, eB0.w};
    const unsigned ea_hi[4] = {eA1.x, eA1.y, eA1.z, eA1.w};
    const unsigned eb_hi[4] = {eB1.x, eB1.y, eB1.z, eB1.w};
    // ---- tile A: w-compute + MFMAs ----
    {
      const unsigned mlo = (unsigned)(mbA >> q8);
      const unsigned mhi = (unsigned)(mbA >> (32 + q8));
      H8U4 a0, a1;
      #pragma unroll
      for (int p = 0; p < 4; ++p) {
        const half2v w2 = __builtin_elementwise_max(c1A * asH2(ea_lo[p]),
                                                    c2A * asH2(eb_lo[p]));
        const unsigned tb = mlo >> (2 * p);
        a0.u[p] = asU(w2) & (((tb & 1u) | ((tb & 2u) << 15)) * 0xFFFFu);
      }
      #pragma unroll
      for (int p = 0; p < 4; ++p) {
        const half2v w2 = __builtin_elementwise_max(c1A * asH2(ea_hi[p]),
                                                    c2A * asH2(eb_hi[p]));
        const unsigned tb = mhi >> (2 * p);
        a1.u[p] = asU(w2) & (((tb & 1u) | ((tb & 2u) << 15)) * 0xFFFFu);
      }
      dpA = __builtin_amdgcn_mfma_f32_16x16x32_f16(a0.v, ones, dpA, 0, 0, 0);
      dpA = __builtin_amdgcn_mfma_f32_16x16x32_f16(a1.v, ones, dpA, 0, 0, 0);
      accA[0] = __builtin_amdgcn_mfma_f32_16x16x32_f16(a0.v, b0, accA[0], 0, 0, 0);
      accA[0] = __builtin_amdgcn_mfma_f32_16x16x32_f16(a1.v, b1, accA[0], 0, 0, 0);
      accA[1] = __builtin_amdgcn_mfma_f32_16x16x32_f16(a0.v, b2, accA[1], 0, 0, 0);
      accA[1] = __builtin_amdgcn_mfma_f32_16x16x32_f16(a1.v, b3, accA[1], 0, 0, 0);
      accA[2] = __builtin_amdgcn_mfma_f32_16x16x32_f16(a0.v, b4, accA[2], 0, 0, 0);
      accA[2] = __builtin_amdgcn_mfma_f32_16x16x32_f16(a1.v, b5, accA[2], 0, 0, 0);
      accA[3] = __builtin_amdgcn_mfma_f32_16x16x32_f16(a0.v, b6, accA[3], 0, 0, 0);
      accA[3] = __builtin_amdgcn_mfma_f32_16x16x32_f16(a1.v, b7, accA[3], 0, 0, 0);
    }
    // ---- tile B: w-compute + MFMAs (reuses E regs + B frags) ----
    {
      const unsigned mlo = (unsigned)(mbB >> q8);
      const unsigned mhi = (unsigned)(mbB >> (32 + q8));
      H8U4 a0, a1;
      #pragma unroll
      for (int p = 0; p < 4; ++p) {
        const half2v w2 = __builtin_elementwise_max(c1B * asH2(ea_lo[p]),
                                                    c2B * asH2(eb_lo[p]));
        const unsigned tb = mlo >> (2 * p);
        a0.u[p] = asU(w2) & (((tb & 1u) | ((tb & 2u) << 15)) * 0xFFFFu);
      }
      #pragma unroll
      for (int p = 0; p < 4; ++p) {
        const half2v w2 = __builtin_elementwise_max(c1B * asH2(ea_hi[p]),
                                                    c2B * asH2(eb_hi[p]));
        const unsigned tb = mhi >> (2 * p);
        a1.u[p] = asU(w2) & (((tb & 1u) | ((tb & 2u) << 15)) * 0xFFFFu);
      }
      dpB = __builtin_amdgcn_mfma_f32_16x16x32_f16(a0.v, ones, dpB, 0, 0, 0);
      dpB = __builtin_amdgcn_mfma_f32_16x16x32_f16(a1.v, ones, dpB, 0, 0, 0);
      accB[0] = __builtin_amdgcn_mfma_f32_16x16x32_f16(a0.v, b0, accB[0], 0, 0, 0);
      accB[0] = __builtin_amdgcn_mfma_f32_16x16x32_f16(a1.v, b1, accB[0], 0, 0, 0);
      accB[1] = __builtin_amdgcn_mfma_f32_16x16x32_f16(a0.v, b2, accB[1], 0, 0, 0);
      accB[1] = __builtin_amdgcn_mfma_f32_16x16x32_f16(a1.v, b3, accB[1], 0, 0, 0);
      accB[2] = __builtin_amdgcn_mfma_f32_16x16x32_f16(a0.v, b4, accB[2], 0, 0, 0);
      accB[2] = __builtin_amdgcn_mfma_f32_16x16x32_f16(a1.v, b5, accB[2], 0, 0, 0);
      accB[3] = __builtin_amdgcn_mfma_f32_16x16x32_f16(a0.v, b6, accB[3], 0, 0, 0);
      accB[3] = __builtin_amdgcn_mfma_f32_16x16x32_f16(a1.v, b7, accB[3], 0, 0, 0);
    }
  }

  // ---- phase A epilogue (rows n0..n0+15) ----
  #pragma unroll
  for (int i = 0; i < 16; ++i) lds_acc[w4][lane][i] = accA[i >> 2][i & 3];
  #pragma unroll
  for (int i = 0; i < 4; ++i) lds_acc[w4][lane][16 + i] = dpA[i];
  __syncthreads();
  #pragma unroll
  for (int j = 0; j < 4; ++j) {
    const int sl = 4 * w4 + j;
    float fa = 0.f, dpt = 0.f;
    #pragma unroll
    for (int w2 = 0; w2 < 4; ++w2) {
      fa  += lds_acc[w2][lane][sl];
      dpt += lds_acc[w2][lane][16 + j];
    }
    float v = fa / dpt;
    v = (v > 0.f) ? v : (__expf(v) - 1.f);
    v = (v > 0.f) ? v : (__expf(v) - 1.f);
    out[(size_t)(n0 + quad * 4 + j) * KF + k * 64 + w4 * 16 + row] = v;
  }
  __syncthreads();
  // ---- phase B epilogue (rows n0+16..n0+31) ----
  #pragma unroll
  for (int i = 0; i < 16; ++i) lds_acc[w4][lane][i] = accB[i >> 2][i & 3];
  #pragma unroll
  for (int i = 0; i < 4; ++i) lds_acc[w4][lane][16 + i] = dpB[i];
  __syncthreads();
  #pragma unroll
  for (int j = 0; j < 4; ++j) {
    const int sl = 4 * w4 + j;
    float fa = 0.f, dpt = 0.f;
    #pragma unroll
    for (int w2 = 0; w2 < 4; ++w2) {
      fa  += lds_acc[w2][lane][sl];
      dpt += lds_acc[w2][lane][16 + j];
    }
    float v = fa / dpt;
    v = (v > 0.f) ? v : (__expf(v) - 1.f);
    v = (v > 0.f) ? v : (__expf(v) - 1.f);
    out[(size_t)(n0 + 16 + quad * 4 + j) * KF + k * 64 + w4 * 16 + row] = v;
  }
}

// ---------- launcher ----------
extern "C" void kernel_launch(void* const* d_in, const int* in_sizes, int n_in,
                              void* d_out, int out_size, void* d_ws, size_t ws_size,
                              hipStream_t stream) {
  const float* x    = (const float*)d_in[0];   // (4096,256) fp32
  const float* Ww   = (const float*)d_in[1];   // (512,256)  fp32
  const float* Wb   = (const float*)d_in[2];   // (512,)     fp32
  const float* al   = (const float*)d_in[3];   // (1,8,64)   fp32
  const float* ar   = (const float*)d_in[4];   // (1,8,64)   fp32
  const int*   mask = (const int*)d_in[5];     // (1,4096,4096) int32

  float* out      = (float*)d_out;                    // (4096,512) fp32, 8 MB
  float* out_mask = out + (size_t)N_NODES * KF;       // (1,4096,4096) fp32, 64 MB

  const bool use_ws = (ws_size >= (8u << 20));
  char* scratch = use_ws ? (char*)d_ws : (char*)out_mask;
  unsigned short* xeB  = (unsigned short*)scratch;                 // 4 MB
  float*          hl   = (float*)(scratch + (4u << 20));           // 128 KB
  unsigned*       EA   = (unsigned*)(hl + KH * N_NODES);           // 64 KB
  unsigned*       EB   = EA + KH * 2048;                           // 64 KB
  float*          bmax = (float*)(EB + KH * 2048);                 // 8 KB
  unsigned long long* mbitsT = (unsigned long long*)(scratch + (5u << 20)); // 2 MB
  // top of use: 7 MB

  if (use_ws) {
    // fused preamble: 512 xe blocks (compute) + 4096 mask blocks (4x int4/thr)
    preamble<<<512 + (N_NODES * (size_t)N_NODES) / 4096, 256, 0, stream>>>(
        mask, out_mask, mbitsT, x, Ww, Wb, al, ar, xeB, hl, EA, EB, bmax);
    gat_attn<<<128 * KH, 256, 0, stream>>>(mbitsT, hl, bmax, EA, EB, xeB, out);
  } else {
    dim3 ga(N_NODES / 64, KH);
    xe_gemm_k<<<ga, 256, 0, stream>>>(x, Ww, Wb, al, ar, xeB, hl, EA, EB, bmax);
    mask_pack<<<(N_NODES * (size_t)N_NODES) / 256, 256, 0, stream>>>(mask, mbitsT);
    gat_attn<<<128 * KH, 256, 0, stream>>>(mbitsT, hl, bmax, EA, EB, xeB, out);
    mask_copy<<<(N_NODES * (size_t)N_NODES) / (4 * 256), 256, 0, stream>>>(mask, out_mask);
  }
}